// Round 1
// baseline (1868.066 us; speedup 1.0000x reference)
//
#include <hip/hip_runtime.h>
#include <hip/hip_bf16.h>
#include <math.h>

#define N_HEADS 12
#define L_SEQ   2048
#define BATCH   2
#define D_KQ    192
#define D_OUT   1152
#define D_KV    1344   // 192 + 1152
#define D_X     768
#define D_SIDE  384
#define HD_K    16
#define HD_V    96

// ---------------------------------------------------------------------------
// Tiled f32 GEMM: C[M,N] = concat(A1[:,0:K1], A2[:,0:K2])[M,K] @ W[K,N] + bias
// (pass K1 == K to use only A1). Requires M%64==0, N%64==0, K%16==0.
// Block 256 threads, 64x64 tile, 4x4 micro-tile per thread.
// ---------------------------------------------------------------------------
__global__ __launch_bounds__(256)
void gemm64(const float* __restrict__ A1, const float* __restrict__ A2,
            int K1, int K2,
            const float* __restrict__ W, const float* __restrict__ bias,
            float* __restrict__ C, int M, int N, int K) {
    __shared__ float As[16][65];   // [k][row], padded
    __shared__ float Ws[16][64];   // [k][col]

    const int tid = threadIdx.x;
    const int tx = tid & 15, ty = tid >> 4;
    const int n0 = blockIdx.x * 64, m0 = blockIdx.y * 64;

    // A-tile load mapping: element e = tid*4+q -> row = tid>>2, k = (tid&3)*4+q
    const int arow = tid >> 2, ak = (tid & 3) * 4;
    // W-tile load mapping: kk = tid>>4, c = (tid&15)*4 (+q), float4
    const int wk = tid >> 4, wc = (tid & 15) * 4;

    float acc[4][4] = {};

    for (int kt = 0; kt < K; kt += 16) {
#pragma unroll
        for (int q = 0; q < 4; q++) {
            int k = kt + ak + q;
            float v = (k < K1) ? A1[(size_t)(m0 + arow) * K1 + k]
                               : A2[(size_t)(m0 + arow) * K2 + (k - K1)];
            As[ak + q][arow] = v;
        }
        float4 wv = *reinterpret_cast<const float4*>(
            &W[(size_t)(kt + wk) * N + n0 + wc]);
        *reinterpret_cast<float4*>(&Ws[wk][wc]) = wv;
        __syncthreads();

#pragma unroll
        for (int kk = 0; kk < 16; kk++) {
            float a[4], w[4];
#pragma unroll
            for (int i = 0; i < 4; i++) a[i] = As[kk][ty + 16 * i];
#pragma unroll
            for (int j = 0; j < 4; j++) w[j] = Ws[kk][tx + 16 * j];
#pragma unroll
            for (int i = 0; i < 4; i++)
#pragma unroll
                for (int j = 0; j < 4; j++)
                    acc[i][j] += a[i] * w[j];
        }
        __syncthreads();
    }

#pragma unroll
    for (int i = 0; i < 4; i++) {
        int r = m0 + ty + 16 * i;
#pragma unroll
        for (int j = 0; j < 4; j++) {
            int c = n0 + tx + 16 * j;
            C[(size_t)r * N + c] = acc[i][j] + bias[c];
        }
    }
}

// ---------------------------------------------------------------------------
// Attention for rows 1..L-1. One block (128 threads) per (b, h, row).
// Row i attends j < i. Online softmax over tiles of 64 keys.
// q buffer: [B, L, 192]; kv buffer: [B, L, 1344] (k = [:,:192], v = [:,192:]).
// y buffer: [B, L, 1152] with head-major dim layout (h*96+d).
// ---------------------------------------------------------------------------
__global__ __launch_bounds__(128)
void attn_kernel(const float* __restrict__ qb, const float* __restrict__ kvb,
                 float* __restrict__ yb) {
    const int row = blockIdx.x + 1;         // skip row 0 (output replaced)
    const int h = blockIdx.y;
    const int b = blockIdx.z;
    const int t = threadIdx.x;

    const float* kvbase = kvb + (size_t)b * L_SEQ * D_KV;

    __shared__ float qs[16];
    __shared__ float p[64];
    __shared__ float red[2];

    if (t < 16) qs[t] = qb[((size_t)b * L_SEQ + row) * D_KQ + h * HD_K + t];
    __syncthreads();

    float m = -INFINITY, l = 0.f, acc = 0.f;
    const int jmax = row;

    for (int j0 = 0; j0 < jmax; j0 += 64) {
        const int n = min(64, jmax - j0);

        if (t < 64) {
            float s = -INFINITY;
            if (t < n) {
                const float4* kp = reinterpret_cast<const float4*>(
                    kvbase + (size_t)(j0 + t) * D_KV + h * HD_K);
                float4 k0 = kp[0], k1 = kp[1], k2 = kp[2], k3 = kp[3];
                float d =
                    qs[0]  * k0.x + qs[1]  * k0.y + qs[2]  * k0.z + qs[3]  * k0.w +
                    qs[4]  * k1.x + qs[5]  * k1.y + qs[6]  * k1.z + qs[7]  * k1.w +
                    qs[8]  * k2.x + qs[9]  * k2.y + qs[10] * k2.z + qs[11] * k2.w +
                    qs[12] * k3.x + qs[13] * k3.y + qs[14] * k3.z + qs[15] * k3.w;
                s = d * 0.25f;   // 1/sqrt(16)
            }
            float mt = s;
#pragma unroll
            for (int off = 32; off > 0; off >>= 1)
                mt = fmaxf(mt, __shfl_xor(mt, off));
            float mnew = fmaxf(m, mt);
            float pv = (t < n) ? __expf(s - mnew) : 0.f;
            p[t] = pv;
            float ps = pv;
#pragma unroll
            for (int off = 32; off > 0; off >>= 1)
                ps += __shfl_xor(ps, off);
            if (t == 0) { red[0] = mnew; red[1] = ps; }
        }
        __syncthreads();

        const float mnew = red[0];
        const float psum = red[1];
        const float scale = (m == -INFINITY) ? 0.f : __expf(m - mnew);
        l = l * scale + psum;
        m = mnew;

        if (t < 96) {
            float a = acc * scale;
            const float* vp = kvbase + (size_t)j0 * D_KV + D_KQ + h * HD_V + t;
#pragma unroll 4
            for (int j = 0; j < n; j++) a += p[j] * vp[(size_t)j * D_KV];
            acc = a;
        }
        __syncthreads();   // protect p/red before next tile
    }

    if (t < 96)
        yb[((size_t)b * L_SEQ + row) * D_OUT + h * HD_V + t] = acc / l;
}

// ---------------------------------------------------------------------------
// first = side[:,0] @ Wemb + bemb  -> y[:, 0, :]
// ---------------------------------------------------------------------------
__global__ __launch_bounds__(128)
void first_kernel(const float* __restrict__ side, const float* __restrict__ Wemb,
                  const float* __restrict__ bemb, float* __restrict__ yb) {
    const int o = blockIdx.x * 128 + threadIdx.x;   // 0..1151
    const int b = blockIdx.y;
    const float* s = side + (size_t)b * L_SEQ * D_SIDE;
    float acc = bemb[o];
    for (int k = 0; k < D_SIDE; k++)
        acc += s[k] * Wemb[(size_t)k * D_OUT + o];
    yb[(size_t)b * L_SEQ * D_OUT + o] = acc;
}

// ---------------------------------------------------------------------------
extern "C" void kernel_launch(void* const* d_in, const int* in_sizes, int n_in,
                              void* d_out, int out_size, void* d_ws, size_t ws_size,
                              hipStream_t stream) {
    const float* x     = (const float*)d_in[0];
    const float* side  = (const float*)d_in[1];
    const float* Wq    = (const float*)d_in[2];
    const float* bq    = (const float*)d_in[3];
    const float* Wkv   = (const float*)d_in[4];
    const float* bkv   = (const float*)d_in[5];
    const float* Wproj = (const float*)d_in[6];
    const float* bproj = (const float*)d_in[7];
    const float* Wemb  = (const float*)d_in[8];
    const float* bemb  = (const float*)d_in[9];
    float* out = (float*)d_out;

    float* ws = (float*)d_ws;
    float* qbuf  = ws;                              // 4096*192  = 786432 floats
    float* kvbuf = ws + 786432;                     // 4096*1344 = 5505024 floats
    float* ybuf  = ws + 786432 + 5505024;           // 4096*1152 = 4718592 floats

    const int M = BATCH * L_SEQ;   // 4096

    // q = side @ Wq + bq                         [4096,384]x[384,192]
    gemm64<<<dim3(D_KQ / 64, M / 64), 256, 0, stream>>>(
        side, side, D_SIDE, D_SIDE, Wq, bq, qbuf, M, D_KQ, D_SIDE);

    // kv = concat(x, side) @ Wkv + bkv           [4096,1152]x[1152,1344]
    gemm64<<<dim3(D_KV / 64, M / 64), 256, 0, stream>>>(
        x, side, D_X, D_SIDE, Wkv, bkv, kvbuf, M, D_KV, D_X + D_SIDE);

    // attention for rows 1..L-1
    attn_kernel<<<dim3(L_SEQ - 1, N_HEADS, BATCH), 128, 0, stream>>>(
        qbuf, kvbuf, ybuf);

    // first-token override (row 0)
    first_kernel<<<dim3(D_OUT / 128, BATCH), 128, 0, stream>>>(
        side, Wemb, bemb, ybuf);

    // out = y @ Wproj + bproj                    [4096,1152]x[1152,1152]
    gemm64<<<dim3(D_OUT / 64, M / 64), 256, 0, stream>>>(
        ybuf, ybuf, D_OUT, D_OUT, Wproj, bproj, out, M, D_OUT, D_OUT);
}

// Round 2
// 1124.481 us; speedup vs baseline: 1.6613x; 1.6613x over previous
//
#include <hip/hip_runtime.h>
#include <hip/hip_bf16.h>
#include <math.h>

#define N_HEADS 12
#define L_SEQ   2048
#define BATCH   2
#define D_KQ    192
#define D_OUT   1152
#define D_KV    1344   // 192 + 1152
#define D_X     768
#define D_SIDE  384
#define HD_K    16
#define HD_V    96

// ---------------------------------------------------------------------------
// Tiled f32 GEMM: C[M,N] = concat(A1[:,0:K1], A2[:,0:K2])[M,K] @ W[K,N] + bias
// ---------------------------------------------------------------------------
__global__ __launch_bounds__(256)
void gemm64(const float* __restrict__ A1, const float* __restrict__ A2,
            int K1, int K2,
            const float* __restrict__ W, const float* __restrict__ bias,
            float* __restrict__ C, int M, int N, int K) {
    __shared__ float As[16][65];   // [k][row], padded
    __shared__ float Ws[16][64];   // [k][col]

    const int tid = threadIdx.x;
    const int tx = tid & 15, ty = tid >> 4;
    const int n0 = blockIdx.x * 64, m0 = blockIdx.y * 64;

    const int arow = tid >> 2, ak = (tid & 3) * 4;
    const int wk = tid >> 4, wc = (tid & 15) * 4;

    float acc[4][4] = {};

    for (int kt = 0; kt < K; kt += 16) {
#pragma unroll
        for (int q = 0; q < 4; q++) {
            int k = kt + ak + q;
            float v = (k < K1) ? A1[(size_t)(m0 + arow) * K1 + k]
                               : A2[(size_t)(m0 + arow) * K2 + (k - K1)];
            As[ak + q][arow] = v;
        }
        float4 wv = *reinterpret_cast<const float4*>(
            &W[(size_t)(kt + wk) * N + n0 + wc]);
        *reinterpret_cast<float4*>(&Ws[wk][wc]) = wv;
        __syncthreads();

#pragma unroll
        for (int kk = 0; kk < 16; kk++) {
            float a[4], w[4];
#pragma unroll
            for (int i = 0; i < 4; i++) a[i] = As[kk][ty + 16 * i];
#pragma unroll
            for (int j = 0; j < 4; j++) w[j] = Ws[kk][tx + 16 * j];
#pragma unroll
            for (int i = 0; i < 4; i++)
#pragma unroll
                for (int j = 0; j < 4; j++)
                    acc[i][j] += a[i] * w[j];
        }
        __syncthreads();
    }

#pragma unroll
    for (int i = 0; i < 4; i++) {
        int r = m0 + ty + 16 * i;
#pragma unroll
        for (int j = 0; j < 4; j++) {
            int c = n0 + tx + 16 * j;
            C[(size_t)r * N + c] = acc[i][j] + bias[c];
        }
    }
}

// ---------------------------------------------------------------------------
// Flash-style attention. One block = 64 query rows x 1 head. 256 threads =
// 4 waves; wave w owns V-dims [w*24, w*24+24); lane = query row within tile.
// K/V tiles staged in LDS, V reads are wave-wide broadcasts.
// Row 0's output is garbage (l=0 -> NaN) and is overwritten by first_kernel
// before the proj GEMM.
// ---------------------------------------------------------------------------
__global__ __launch_bounds__(256)
void attn_kernel(const float* __restrict__ qb, const float* __restrict__ kvb,
                 float* __restrict__ yb) {
    const int qt = blockIdx.x;           // q-tile index (64 rows)
    const int h  = blockIdx.y;
    const int b  = blockIdx.z;
    const int tid  = threadIdx.x;
    const int w    = tid >> 6;           // wave 0..3
    const int lane = tid & 63;           // row within q-tile
    const int q0 = qt * 64;

    __shared__ float4 Ks[64][4];         // [key][dk/4]       4 KB
    __shared__ float4 Vs[64][24];        // [key][dv/4]      24 KB
    __shared__ float  Ps[64 * 65];       // [row][key] pad   16.25 KB
    __shared__ float  pmax_s[64 * 5];    // [row][wave] pad
    __shared__ float  psum_s[64 * 5];

    const float* kvbase = kvb + (size_t)b * L_SEQ * D_KV;

    // Q for this lane's row -> registers
    float4 q4[4];
    {
        const float4* qp = reinterpret_cast<const float4*>(
            qb + ((size_t)b * L_SEQ + q0 + lane) * D_KQ + h * HD_K);
#pragma unroll
        for (int i = 0; i < 4; i++) q4[i] = qp[i];
    }

    float m = -INFINITY, l = 0.f;
    float4 acc[6] = {};                  // 24 dims per wave

    for (int t2 = 0; t2 <= qt; t2++) {
        const int j0 = t2 * 64;
        const bool diag = (t2 == qt);

        __syncthreads();                 // previous tile's LDS reads done

        // ---- stage K tile: 256 float4 ----
        {
            int key = tid >> 2, d4 = tid & 3;
            Ks[key][d4] = *reinterpret_cast<const float4*>(
                kvbase + (size_t)(j0 + key) * D_KV + h * HD_K + d4 * 4);
        }
        // ---- stage V tile: 1536 float4, 6 per thread ----
        {
            int key = tid >> 2;
            const float4* vsrc = reinterpret_cast<const float4*>(
                kvbase + (size_t)(j0 + key) * D_KV + D_KQ + h * HD_V);
#pragma unroll
            for (int r = 0; r < 6; r++) {
                int d4 = (tid & 3) + r * 4;
                Vs[key][d4] = vsrc[d4];
            }
        }
        __syncthreads();

        // ---- scores: wave w computes keys [16w, 16w+16) for all 64 rows ----
        float s_reg[16];
        float pmax = -INFINITY;
#pragma unroll
        for (int kk = 0; kk < 16; kk++) {
            const int jj = w * 16 + kk;
            float4 k0 = Ks[jj][0], k1 = Ks[jj][1], k2 = Ks[jj][2], k3 = Ks[jj][3];
            float d =
                q4[0].x * k0.x + q4[0].y * k0.y + q4[0].z * k0.z + q4[0].w * k0.w +
                q4[1].x * k1.x + q4[1].y * k1.y + q4[1].z * k1.z + q4[1].w * k1.w +
                q4[2].x * k2.x + q4[2].y * k2.y + q4[2].z * k2.z + q4[2].w * k2.w +
                q4[3].x * k3.x + q4[3].y * k3.y + q4[3].z * k3.z + q4[3].w * k3.w;
            float sv = d * 0.25f;        // 1/sqrt(16)
            s_reg[kk] = sv;
            bool valid = (!diag) || (jj < lane);
            if (valid) pmax = fmaxf(pmax, sv);
        }
        pmax_s[lane * 5 + w] = pmax;
        __syncthreads();

        // ---- row max across waves (each wave redundantly) ----
        float tm = fmaxf(fmaxf(pmax_s[lane * 5 + 0], pmax_s[lane * 5 + 1]),
                         fmaxf(pmax_s[lane * 5 + 2], pmax_s[lane * 5 + 3]));
        float mnew = fmaxf(m, tm);
        float scale = (m == -INFINITY) ? 0.f : __expf(m - mnew);

        // ---- exp + partial sums ----
        float psum = 0.f;
#pragma unroll
        for (int kk = 0; kk < 16; kk++) {
            const int jj = w * 16 + kk;
            bool valid = (!diag) || (jj < lane);
            float pv = valid ? __expf(s_reg[kk] - mnew) : 0.f;
            Ps[lane * 65 + jj] = pv;
            psum += pv;
        }
        psum_s[lane * 5 + w] = psum;
        __syncthreads();

        float tsum = psum_s[lane * 5 + 0] + psum_s[lane * 5 + 1] +
                     psum_s[lane * 5 + 2] + psum_s[lane * 5 + 3];
        l = l * scale + tsum;
        m = mnew;

        // ---- O update: acc[d] = acc[d]*scale + sum_j P[row][j] * V[j][d] ----
#pragma unroll
        for (int d6 = 0; d6 < 6; d6++) {
            acc[d6].x *= scale; acc[d6].y *= scale;
            acc[d6].z *= scale; acc[d6].w *= scale;
        }
        for (int jj = 0; jj < 64; jj++) {
            float pv = Ps[lane * 65 + jj];
#pragma unroll
            for (int d6 = 0; d6 < 6; d6++) {
                float4 v = Vs[jj][w * 6 + d6];
                acc[d6].x += pv * v.x; acc[d6].y += pv * v.y;
                acc[d6].z += pv * v.z; acc[d6].w += pv * v.w;
            }
        }
    }

    // ---- write out: y[b, q0+lane, h*96 + w*24 + ...] ----
    {
        float inv = 1.f / l;             // row 0: 0/0 -> NaN, overwritten later
        float4* op = reinterpret_cast<float4*>(
            yb + ((size_t)b * L_SEQ + q0 + lane) * D_OUT + h * HD_V);
#pragma unroll
        for (int d6 = 0; d6 < 6; d6++) {
            float4 o = acc[d6];
            o.x *= inv; o.y *= inv; o.z *= inv; o.w *= inv;
            op[w * 6 + d6] = o;
        }
    }
}

// ---------------------------------------------------------------------------
// first = side[:,0] @ Wemb + bemb  -> y[:, 0, :]
// ---------------------------------------------------------------------------
__global__ __launch_bounds__(128)
void first_kernel(const float* __restrict__ side, const float* __restrict__ Wemb,
                  const float* __restrict__ bemb, float* __restrict__ yb) {
    const int o = blockIdx.x * 128 + threadIdx.x;   // 0..1151
    const int b = blockIdx.y;
    const float* s = side + (size_t)b * L_SEQ * D_SIDE;
    float acc = bemb[o];
    for (int k = 0; k < D_SIDE; k++)
        acc += s[k] * Wemb[(size_t)k * D_OUT + o];
    yb[(size_t)b * L_SEQ * D_OUT + o] = acc;
}

// ---------------------------------------------------------------------------
extern "C" void kernel_launch(void* const* d_in, const int* in_sizes, int n_in,
                              void* d_out, int out_size, void* d_ws, size_t ws_size,
                              hipStream_t stream) {
    const float* x     = (const float*)d_in[0];
    const float* side  = (const float*)d_in[1];
    const float* Wq    = (const float*)d_in[2];
    const float* bq    = (const float*)d_in[3];
    const float* Wkv   = (const float*)d_in[4];
    const float* bkv   = (const float*)d_in[5];
    const float* Wproj = (const float*)d_in[6];
    const float* bproj = (const float*)d_in[7];
    const float* Wemb  = (const float*)d_in[8];
    const float* bemb  = (const float*)d_in[9];
    float* out = (float*)d_out;

    float* ws = (float*)d_ws;
    float* qbuf  = ws;                              // 4096*192  floats
    float* kvbuf = ws + 786432;                     // 4096*1344 floats
    float* ybuf  = ws + 786432 + 5505024;           // 4096*1152 floats

    const int M = BATCH * L_SEQ;   // 4096

    // q = side @ Wq + bq                         [4096,384]x[384,192]
    gemm64<<<dim3(D_KQ / 64, M / 64), 256, 0, stream>>>(
        side, side, D_SIDE, D_SIDE, Wq, bq, qbuf, M, D_KQ, D_SIDE);

    // kv = concat(x, side) @ Wkv + bkv           [4096,1152]x[1152,1344]
    gemm64<<<dim3(D_KV / 64, M / 64), 256, 0, stream>>>(
        x, side, D_X, D_SIDE, Wkv, bkv, kvbuf, M, D_KV, D_X + D_SIDE);

    // attention: 64-row q-tiles
    attn_kernel<<<dim3(L_SEQ / 64, N_HEADS, BATCH), 256, 0, stream>>>(
        qbuf, kvbuf, ybuf);

    // first-token override (row 0) -- must run before proj GEMM
    first_kernel<<<dim3(D_OUT / 128, BATCH), 128, 0, stream>>>(
        side, Wemb, bemb, ybuf);

    // out = y @ Wproj + bproj                    [4096,1152]x[1152,1152]
    gemm64<<<dim3(D_OUT / 64, M / 64), 256, 0, stream>>>(
        ybuf, ybuf, D_OUT, D_OUT, Wproj, bproj, out, M, D_OUT, D_OUT);
}

// Round 4
// 782.063 us; speedup vs baseline: 2.3886x; 1.4378x over previous
//
#include <hip/hip_runtime.h>
#include <hip/hip_bf16.h>
#include <math.h>

#define N_HEADS 12
#define L_SEQ   2048
#define BATCH   2
#define D_KQ    192
#define D_OUT   1152
#define D_KV    1344   // 192 + 1152
#define D_X     768
#define D_SIDE  384
#define HD_K    16
#define HD_V    96
#define M_ROWS  4096
#define NITEMS  (32 * N_HEADS * BATCH)   // 768 attention work items

typedef __attribute__((ext_vector_type(8))) short bf16x8;
typedef __attribute__((ext_vector_type(4))) float f32x4;

__device__ inline float  b2f(ushort u){ union{uint i; float f;} v; v.i=(uint)u<<16; return v.f; }
__device__ inline float  lo2f(uint u){ union{uint i; float f;} v; v.i=u<<16;        return v.f; }
__device__ inline float  hi2f(uint u){ union{uint i; float f;} v; v.i=u&0xffff0000u;return v.f; }
__device__ inline ushort f2b(float f){ __hip_bfloat16 h = __float2bfloat16(f);
                                       return *reinterpret_cast<ushort*>(&h); }

__device__ inline void gload_lds16(const ushort* g, ushort* l) {
    __builtin_amdgcn_global_load_lds(
        (const __attribute__((address_space(1))) void*)g,
        (__attribute__((address_space(3))) void*)l, 16, 0, 0);
}

// ---------------------------------------------------------------------------
// f32 -> bf16 copy (optionally strided dest for concat). w4 = width/4.
// ---------------------------------------------------------------------------
__global__ __launch_bounds__(256)
void cvt_f32_bf16(const float* __restrict__ src, int sstride,
                  ushort* __restrict__ dst, int dstride, int w4, int rows) {
    int gid = blockIdx.x * 256 + threadIdx.x;
    if (gid >= w4 * rows) return;
    int r = gid / w4, c = gid - r * w4;
    float4 v = *reinterpret_cast<const float4*>(&src[(size_t)r * sstride + c * 4]);
    ushort4 o = make_ushort4(f2b(v.x), f2b(v.y), f2b(v.z), f2b(v.w));
    *reinterpret_cast<ushort4*>(&dst[(size_t)r * dstride + c * 4]) = o;
}

// ---------------------------------------------------------------------------
// W[K][N] f32  ->  Wt[Npad][K] bf16 (rows >= N zero-filled). K%32==0, N%32==0.
// ---------------------------------------------------------------------------
__global__ __launch_bounds__(256)
void transpose_cvt(const float* __restrict__ W, ushort* __restrict__ Wt,
                   int K, int N, int Npad) {
    __shared__ float t[32][33];
    const int n0 = blockIdx.x * 32, k0 = blockIdx.y * 32;
    const int tx = threadIdx.x & 31, ty = threadIdx.x >> 5;   // ty 0..7
#pragma unroll
    for (int i = 0; i < 4; i++) {
        int n = n0 + tx;
        t[ty + i * 8][tx] = (n < N) ? W[(size_t)(k0 + ty + i * 8) * N + n] : 0.f;
    }
    __syncthreads();
#pragma unroll
    for (int i = 0; i < 4; i++) {
        int n = n0 + ty + i * 8;
        Wt[(size_t)n * K + k0 + tx] = f2b(t[tx][ty + i * 8]);
    }
}

// ---------------------------------------------------------------------------
// bf16 MFMA GEMM: C[M,N] = A[M,K] @ Wt[N,K]^T + bias.  128x128 tile, BK=32,
// 4 waves x (64x64), 16x16x32 MFMA, global_load_lds(16) staging.
// Wt has >= gridDim.x*128 rows (padded with zeros). Stores masked to col<N.
// ---------------------------------------------------------------------------
template<int STORE_BF16>
__global__ __launch_bounds__(256)
void gemm_mfma(const ushort* __restrict__ A, const ushort* __restrict__ Bt,
               const float* __restrict__ bias, void* __restrict__ Cv,
               int M, int N, int K) {
    __shared__ ushort As[128 * 32];
    __shared__ ushort Bs[128 * 32];
    const int tid = threadIdx.x;
    const int w = tid >> 6, lane = tid & 63;
    const int wr = w >> 1, wc = w & 1;
    const int n0 = blockIdx.x * 128, m0 = blockIdx.y * 128;
    const int l4 = lane & 3, lrow = lane >> 2;
    const int kgrp = lane >> 4, l16 = lane & 15;

    f32x4 acc[4][4];
#pragma unroll
    for (int i = 0; i < 4; i++)
#pragma unroll
        for (int j = 0; j < 4; j++)
            acc[i][j] = (f32x4){0.f, 0.f, 0.f, 0.f};

    for (int kt = 0; kt < K; kt += 32) {
        __syncthreads();
#pragma unroll
        for (int r = 0; r < 2; r++) {
            const int seg = r * 4 + w;              // 0..7, wave-uniform
            const int trow = seg * 16 + lrow;       // tile row this lane loads
            gload_lds16(&A [(size_t)(m0 + trow) * K + kt + l4 * 8], &As[seg * 512]);
            gload_lds16(&Bt[(size_t)(n0 + trow) * K + kt + l4 * 8], &Bs[seg * 512]);
        }
        __syncthreads();

        bf16x8 a[4], b[4];
#pragma unroll
        for (int i = 0; i < 4; i++)
            a[i] = *reinterpret_cast<const bf16x8*>(
                &As[(wr * 64 + i * 16 + l16) * 32 + kgrp * 8]);
#pragma unroll
        for (int j = 0; j < 4; j++)
            b[j] = *reinterpret_cast<const bf16x8*>(
                &Bs[(wc * 64 + j * 16 + l16) * 32 + kgrp * 8]);
#pragma unroll
        for (int i = 0; i < 4; i++)
#pragma unroll
            for (int j = 0; j < 4; j++)
                acc[i][j] = __builtin_amdgcn_mfma_f32_16x16x32_bf16(
                    a[i], b[j], acc[i][j], 0, 0, 0);
    }

    const int rgrp = lane >> 4;
#pragma unroll
    for (int j = 0; j < 4; j++) {
        const int col = n0 + wc * 64 + j * 16 + l16;
        if (col >= N) continue;
        const float bv = bias[col];
#pragma unroll
        for (int i = 0; i < 4; i++) {
            const int row0 = m0 + wr * 64 + i * 16 + rgrp * 4;
#pragma unroll
            for (int rg = 0; rg < 4; rg++) {
                float v = acc[i][j][rg] + bv;
                if (STORE_BF16)
                    ((ushort*)Cv)[(size_t)(row0 + rg) * N + col] = f2b(v);
                else
                    ((float*)Cv)[(size_t)(row0 + rg) * N + col] = v;
            }
        }
    }
}

// ---------------------------------------------------------------------------
// Flash attention, work-queue load-balanced. Item = (qt, h, b), heavy first.
// Block = 256 threads (4 waves); wave w owns V-dims [24w, 24w+24); lane = row.
// bf16 q/kv in, bf16 y out (head-major dim layout h*96+d).
// Row 0 output is garbage (l=0 -> NaN); first_kernel overwrites it.
// ---------------------------------------------------------------------------
__global__ __launch_bounds__(256)
void attn_kernel(const ushort* __restrict__ qb, const ushort* __restrict__ kvb,
                 ushort* __restrict__ yb, int* __restrict__ counter) {
    __shared__ float4 Ks[64][4];       //  4 KB
    __shared__ float4 Vs[64][24];      // 24 KB
    __shared__ ushort Ps[64 * 65];     //  8.1 KB
    __shared__ float  pmax_s[64 * 5];
    __shared__ float  psum_s[64 * 5];
    __shared__ int    item_s;

    const int tid = threadIdx.x;
    const int w = tid >> 6, lane = tid & 63;

    for (;;) {
        __syncthreads();
        if (tid == 0) item_s = atomicAdd(counter, 1);
        __syncthreads();
        const int item = item_s;
        if (item >= NITEMS) return;

        const int qt = 31 - item / (N_HEADS * BATCH);     // heavy tiles first
        const int hb = item % (N_HEADS * BATCH);
        const int h = hb % N_HEADS, b = hb / N_HEADS;

        const size_t qrow = (size_t)b * L_SEQ + qt * 64 + lane;
        const ushort* qp = qb + qrow * D_KQ + h * HD_K;
        float4 q4[4];
        {
            uint4 qa = *reinterpret_cast<const uint4*>(qp);
            uint4 qc = *reinterpret_cast<const uint4*>(qp + 8);
            q4[0] = make_float4(lo2f(qa.x), hi2f(qa.x), lo2f(qa.y), hi2f(qa.y));
            q4[1] = make_float4(lo2f(qa.z), hi2f(qa.z), lo2f(qa.w), hi2f(qa.w));
            q4[2] = make_float4(lo2f(qc.x), hi2f(qc.x), lo2f(qc.y), hi2f(qc.y));
            q4[3] = make_float4(lo2f(qc.z), hi2f(qc.z), lo2f(qc.w), hi2f(qc.w));
        }
        const ushort* kvbase = kvb + (size_t)b * L_SEQ * D_KV;

        float m = -INFINITY, l = 0.f;
        float4 acc[6];
#pragma unroll
        for (int d6 = 0; d6 < 6; d6++) acc[d6] = make_float4(0.f, 0.f, 0.f, 0.f);

        for (int t2 = 0; t2 <= qt; t2++) {
            const int j0 = t2 * 64;
            const bool diag = (t2 == qt);
            __syncthreads();
            {   // stage K (bf16 -> f32)
                int key = tid >> 2, d4 = tid & 3;
                ushort4 kk4 = *reinterpret_cast<const ushort4*>(
                    kvbase + (size_t)(j0 + key) * D_KV + h * HD_K + d4 * 4);
                Ks[key][d4] = make_float4(b2f(kk4.x), b2f(kk4.y), b2f(kk4.z), b2f(kk4.w));
            }
            {   // stage V (bf16 -> f32)
                int key = tid >> 2;
                const ushort* vp = kvbase + (size_t)(j0 + key) * D_KV + D_KQ + h * HD_V;
#pragma unroll
                for (int r = 0; r < 3; r++) {
                    int c = (tid & 3) * 3 + r;          // 8-dim chunk 0..11
                    uint4 u = *reinterpret_cast<const uint4*>(vp + c * 8);
                    Vs[key][c * 2]     = make_float4(lo2f(u.x), hi2f(u.x), lo2f(u.y), hi2f(u.y));
                    Vs[key][c * 2 + 1] = make_float4(lo2f(u.z), hi2f(u.z), lo2f(u.w), hi2f(u.w));
                }
            }
            __syncthreads();

            // scores: wave w -> keys [16w,16w+16) for this lane's row
            float s_reg[16];
            float pmax = -INFINITY;
#pragma unroll
            for (int kk = 0; kk < 16; kk++) {
                const int jj = w * 16 + kk;
                float4 k0v = Ks[jj][0], k1v = Ks[jj][1], k2v = Ks[jj][2], k3v = Ks[jj][3];
                float d =
                    q4[0].x*k0v.x + q4[0].y*k0v.y + q4[0].z*k0v.z + q4[0].w*k0v.w +
                    q4[1].x*k1v.x + q4[1].y*k1v.y + q4[1].z*k1v.z + q4[1].w*k1v.w +
                    q4[2].x*k2v.x + q4[2].y*k2v.y + q4[2].z*k2v.z + q4[2].w*k2v.w +
                    q4[3].x*k3v.x + q4[3].y*k3v.y + q4[3].z*k3v.z + q4[3].w*k3v.w;
                float sv = d * 0.25f;                    // 1/sqrt(16)
                s_reg[kk] = sv;
                if ((!diag) || (jj < lane)) pmax = fmaxf(pmax, sv);
            }
            pmax_s[lane * 5 + w] = pmax;
            __syncthreads();

            float tm = fmaxf(fmaxf(pmax_s[lane * 5 + 0], pmax_s[lane * 5 + 1]),
                             fmaxf(pmax_s[lane * 5 + 2], pmax_s[lane * 5 + 3]));
            float mnew = fmaxf(m, tm);
            float scale = (m == -INFINITY) ? 0.f : __expf(m - mnew);

            float psum = 0.f;
#pragma unroll
            for (int kk = 0; kk < 16; kk++) {
                const int jj = w * 16 + kk;
                bool valid = (!diag) || (jj < lane);
                float pv = valid ? __expf(s_reg[kk] - mnew) : 0.f;
                Ps[lane * 65 + jj] = f2b(pv);
                psum += pv;
            }
            psum_s[lane * 5 + w] = psum;
            __syncthreads();

            float tsum = psum_s[lane * 5 + 0] + psum_s[lane * 5 + 1] +
                         psum_s[lane * 5 + 2] + psum_s[lane * 5 + 3];
            l = l * scale + tsum;
            m = mnew;

#pragma unroll
            for (int d6 = 0; d6 < 6; d6++) {
                acc[d6].x *= scale; acc[d6].y *= scale;
                acc[d6].z *= scale; acc[d6].w *= scale;
            }
            for (int jj = 0; jj < 64; jj++) {
                float pv = b2f(Ps[lane * 65 + jj]);
#pragma unroll
                for (int d6 = 0; d6 < 6; d6++) {
                    float4 vv = Vs[jj][w * 6 + d6];
                    acc[d6].x += pv * vv.x; acc[d6].y += pv * vv.y;
                    acc[d6].z += pv * vv.z; acc[d6].w += pv * vv.w;
                }
            }
        }

        float inv = 1.f / l;
        ushort* op = yb + qrow * D_OUT + h * HD_V + w * 24;
#pragma unroll
        for (int d6 = 0; d6 < 6; d6++) {
            ushort4 o = make_ushort4(f2b(acc[d6].x * inv), f2b(acc[d6].y * inv),
                                     f2b(acc[d6].z * inv), f2b(acc[d6].w * inv));
            *reinterpret_cast<ushort4*>(op + d6 * 4) = o;
        }
    }
}

// ---------------------------------------------------------------------------
// first = side[:,0] @ Wemb + bemb  -> y[:, 0, :]  (bf16)
// ---------------------------------------------------------------------------
__global__ __launch_bounds__(128)
void first_kernel(const float* __restrict__ side, const float* __restrict__ Wemb,
                  const float* __restrict__ bemb, ushort* __restrict__ yb) {
    const int o = blockIdx.x * 128 + threadIdx.x;   // 0..1151
    const int b = blockIdx.y;
    const float* s = side + (size_t)b * L_SEQ * D_SIDE;
    float acc = bemb[o];
    for (int k = 0; k < D_SIDE; k++)
        acc += s[k] * Wemb[(size_t)k * D_OUT + o];
    yb[(size_t)b * L_SEQ * D_OUT + o] = f2b(acc);
}

// ---------------------------------------------------------------------------
extern "C" void kernel_launch(void* const* d_in, const int* in_sizes, int n_in,
                              void* d_out, int out_size, void* d_ws, size_t ws_size,
                              hipStream_t stream) {
    const float* x     = (const float*)d_in[0];
    const float* side  = (const float*)d_in[1];
    const float* Wq    = (const float*)d_in[2];
    const float* bq    = (const float*)d_in[3];
    const float* Wkv   = (const float*)d_in[4];
    const float* bkv   = (const float*)d_in[5];
    const float* Wproj = (const float*)d_in[6];
    const float* bproj = (const float*)d_in[7];
    const float* Wemb  = (const float*)d_in[8];
    const float* bemb  = (const float*)d_in[9];
    float* out = (float*)d_out;

    char* ws = (char*)d_ws;
    ushort* xs_bf   = (ushort*)(ws + 0);          // [4096][1152]
    ushort* side_bf = (ushort*)(ws + 9437184);    // [4096][384]
    ushort* wq_t    = (ushort*)(ws + 12582912);   // [256][384]
    ushort* wkv_t   = (ushort*)(ws + 12779520);   // [1408][1152]
    ushort* wproj_t = (ushort*)(ws + 16023552);   // [1152][1152]
    ushort* qbuf    = (ushort*)(ws + 18677760);   // [4096][192]
    ushort* kvbuf   = (ushort*)(ws + 20250624);   // [4096][1344]
    ushort* ybuf    = (ushort*)(ws + 31260672);   // [4096][1152]
    int*    counter = (int*)   (ws + 40697856);

    // conversions to bf16 (+ concat, + weight transposes with zero-padding)
    // grids: one thread per float4 item  -> (w4*rows + 255)/256 blocks
    {
        int items_x  = (D_X / 4) * M_ROWS;      // 786432 -> 3072 blocks
        int items_sd = (D_SIDE / 4) * M_ROWS;   // 393216 -> 1536 blocks
        cvt_f32_bf16<<<(items_x  + 255) / 256, 256, 0, stream>>>(
            x,    D_X,    xs_bf,       D_OUT,  D_X / 4,    M_ROWS);
        cvt_f32_bf16<<<(items_sd + 255) / 256, 256, 0, stream>>>(
            side, D_SIDE, xs_bf + D_X, D_OUT,  D_SIDE / 4, M_ROWS);
        cvt_f32_bf16<<<(items_sd + 255) / 256, 256, 0, stream>>>(
            side, D_SIDE, side_bf,     D_SIDE, D_SIDE / 4, M_ROWS);
    }
    transpose_cvt<<<dim3(8, 12),  256, 0, stream>>>(Wq,    wq_t,    D_SIDE, D_KQ,  256);
    transpose_cvt<<<dim3(44, 36), 256, 0, stream>>>(Wkv,   wkv_t,   D_OUT,  D_KV,  1408);
    transpose_cvt<<<dim3(36, 36), 256, 0, stream>>>(Wproj, wproj_t, D_OUT,  D_OUT, 1152);
    hipMemsetAsync(counter, 0, 4, stream);

    // q = side @ Wq + bq            -> bf16 [4096][192]
    gemm_mfma<1><<<dim3(2, 32),  256, 0, stream>>>(side_bf, wq_t,    bq,    qbuf,  M_ROWS, D_KQ,  D_SIDE);
    // kv = [x,side] @ Wkv + bkv     -> bf16 [4096][1344]
    gemm_mfma<1><<<dim3(11, 32), 256, 0, stream>>>(xs_bf,   wkv_t,   bkv,   kvbuf, M_ROWS, D_KV,  D_OUT);
    // attention -> ybuf bf16
    attn_kernel<<<512, 256, 0, stream>>>(qbuf, kvbuf, ybuf, counter);
    // first-token override (row 0 of each batch)
    first_kernel<<<dim3(9, BATCH), 128, 0, stream>>>(side, Wemb, bemb, ybuf);
    // out = y @ Wproj + bproj       -> f32
    gemm_mfma<0><<<dim3(9, 32),  256, 0, stream>>>(ybuf,    wproj_t, bproj, out,   M_ROWS, D_OUT, D_OUT);
}

// Round 5
// 321.910 us; speedup vs baseline: 5.8031x; 2.4294x over previous
//
#include <hip/hip_runtime.h>
#include <hip/hip_bf16.h>
#include <math.h>

#define N_HEADS 12
#define L_SEQ   2048
#define BATCH   2
#define D_KQ    192
#define D_OUT   1152
#define D_KV    1344   // 192 + 1152
#define D_X     768
#define D_SIDE  384
#define HD_K    16
#define HD_V    96
#define M_ROWS  4096

typedef __attribute__((ext_vector_type(8))) short bf16x8;
typedef __attribute__((ext_vector_type(4))) float f32x4;

__device__ inline float  b2f(ushort u){ union{uint i; float f;} v; v.i=(uint)u<<16; return v.f; }
__device__ inline ushort f2b(float f){ __hip_bfloat16 h = __float2bfloat16(f);
                                       return *reinterpret_cast<ushort*>(&h); }

__device__ inline void gload_lds16(const ushort* g, ushort* l) {
    __builtin_amdgcn_global_load_lds(
        (const __attribute__((address_space(1))) void*)g,
        (__attribute__((address_space(3))) void*)l, 16, 0, 0);
}

// swizzled ushort index for [R][64] bf16 LDS tiles (XOR bits 3..5 with row&7)
#define SWZ(r, c) ((((r) * 64) + (c)) ^ (((r) & 7) << 3))

// ---------------------------------------------------------------------------
// f32 -> bf16 copy (optionally strided dest for concat). w4 = width/4.
// ---------------------------------------------------------------------------
__global__ __launch_bounds__(256)
void cvt_f32_bf16(const float* __restrict__ src, int sstride,
                  ushort* __restrict__ dst, int dstride, int w4, int rows) {
    int gid = blockIdx.x * 256 + threadIdx.x;
    if (gid >= w4 * rows) return;
    int r = gid / w4, c = gid - r * w4;
    float4 v = *reinterpret_cast<const float4*>(&src[(size_t)r * sstride + c * 4]);
    ushort4 o = make_ushort4(f2b(v.x), f2b(v.y), f2b(v.z), f2b(v.w));
    *reinterpret_cast<ushort4*>(&dst[(size_t)r * dstride + c * 4]) = o;
}

// ---------------------------------------------------------------------------
// W[K][N] f32  ->  Wt[Npad][K] bf16 (rows >= N zero-filled). K%32==0, N%32==0.
// ---------------------------------------------------------------------------
__global__ __launch_bounds__(256)
void transpose_cvt(const float* __restrict__ W, ushort* __restrict__ Wt,
                   int K, int N, int Npad) {
    __shared__ float t[32][33];
    const int n0 = blockIdx.x * 32, k0 = blockIdx.y * 32;
    const int tx = threadIdx.x & 31, ty = threadIdx.x >> 5;   // ty 0..7
#pragma unroll
    for (int i = 0; i < 4; i++) {
        int n = n0 + tx;
        t[ty + i * 8][tx] = (n < N) ? W[(size_t)(k0 + ty + i * 8) * N + n] : 0.f;
    }
    __syncthreads();
#pragma unroll
    for (int i = 0; i < 4; i++) {
        int n = n0 + ty + i * 8;
        Wt[(size_t)n * K + k0 + tx] = f2b(t[tx][ty + i * 8]);
    }
}

// ---------------------------------------------------------------------------
// bf16 MFMA GEMM: C[M,N] = A[M,K] @ Wt[N,K]^T + bias.  128x128 tile, BK=32,
// 4 waves x (64x64), 16x16x32 MFMA, global_load_lds(16) staging.
// ---------------------------------------------------------------------------
template<int STORE_BF16>
__global__ __launch_bounds__(256)
void gemm_mfma(const ushort* __restrict__ A, const ushort* __restrict__ Bt,
               const float* __restrict__ bias, void* __restrict__ Cv,
               int M, int N, int K) {
    __shared__ ushort As[128 * 32];
    __shared__ ushort Bs[128 * 32];
    const int tid = threadIdx.x;
    const int w = tid >> 6, lane = tid & 63;
    const int wr = w >> 1, wc = w & 1;
    const int n0 = blockIdx.x * 128, m0 = blockIdx.y * 128;
    const int l4 = lane & 3, lrow = lane >> 2;
    const int kgrp = lane >> 4, l16 = lane & 15;

    f32x4 acc[4][4];
#pragma unroll
    for (int i = 0; i < 4; i++)
#pragma unroll
        for (int j = 0; j < 4; j++)
            acc[i][j] = (f32x4){0.f, 0.f, 0.f, 0.f};

    for (int kt = 0; kt < K; kt += 32) {
        __syncthreads();
#pragma unroll
        for (int r = 0; r < 2; r++) {
            const int seg = r * 4 + w;              // 0..7, wave-uniform
            const int trow = seg * 16 + lrow;       // tile row this lane loads
            gload_lds16(&A [(size_t)(m0 + trow) * K + kt + l4 * 8], &As[seg * 512]);
            gload_lds16(&Bt[(size_t)(n0 + trow) * K + kt + l4 * 8], &Bs[seg * 512]);
        }
        __syncthreads();

        bf16x8 a[4], b[4];
#pragma unroll
        for (int i = 0; i < 4; i++)
            a[i] = *reinterpret_cast<const bf16x8*>(
                &As[(wr * 64 + i * 16 + l16) * 32 + kgrp * 8]);
#pragma unroll
        for (int j = 0; j < 4; j++)
            b[j] = *reinterpret_cast<const bf16x8*>(
                &Bs[(wc * 64 + j * 16 + l16) * 32 + kgrp * 8]);
#pragma unroll
        for (int i = 0; i < 4; i++)
#pragma unroll
            for (int j = 0; j < 4; j++)
                acc[i][j] = __builtin_amdgcn_mfma_f32_16x16x32_bf16(
                    a[i], b[j], acc[i][j], 0, 0, 0);
    }

    const int rgrp = lane >> 4;
#pragma unroll
    for (int j = 0; j < 4; j++) {
        const int col = n0 + wc * 64 + j * 16 + l16;
        if (col >= N) continue;
        const float bv = bias[col];
#pragma unroll
        for (int i = 0; i < 4; i++) {
            const int row0 = m0 + wr * 64 + i * 16 + rgrp * 4;
#pragma unroll
            for (int rg = 0; rg < 4; rg++) {
                float v = acc[i][j][rg] + bv;
                if (STORE_BF16)
                    ((ushort*)Cv)[(size_t)(row0 + rg) * N + col] = f2b(v);
                else
                    ((float*)Cv)[(size_t)(row0 + rg) * N + col] = v;
            }
        }
    }
}

// ---------------------------------------------------------------------------
// MFMA flash attention. One block = 64 q-rows x 1 head; 4 waves, wave w owns
// q-rows [w*16, w*16+16). Grid = 768 (all items co-resident, 6 blocks/CU).
// QK^T and PV on matrix cores (16x16x32 bf16, dk padded 16->32).
// S/P C-layout: lane holds col = key/dim = lane&15, rows = (lane>>4)*4 + reg.
// Row 0 of the sequence produces NaN (l=0); first_kernel overwrites it.
// ---------------------------------------------------------------------------
__global__ __launch_bounds__(256)
void attn_mfma(const ushort* __restrict__ qb, const ushort* __restrict__ kvb,
               ushort* __restrict__ yb) {
    __shared__ ushort Ks2[64 * 40];      // [key][40] (16 dk + 16 zero + 8 pad) 5 KB
    __shared__ ushort Vt[96 * 64];       // [dim][key], XOR-swizzled           12 KB
    __shared__ ushort Ps[4][16 * 64];    // per-wave [row][key], swizzled       8 KB

    const int tid  = threadIdx.x;
    const int w    = tid >> 6, lane = tid & 63;
    const int l16  = lane & 15, kgrp = lane >> 4;

    const int item = blockIdx.x;                 // 768 = 32 qt * 24 (h,b)
    const int qt = item & 31, hb = item >> 5;
    const int h  = hb % N_HEADS, b = hb / N_HEADS;

    const ushort* kvbase = kvb + (size_t)b * L_SEQ * D_KV;
    const int rowbase = qt * 64;

    // Q fragment (constant across tiles): row = w*16+l16, k-chunk kgrp*8 (pad 0)
    bf16x8 qf = {0, 0, 0, 0, 0, 0, 0, 0};
    if (kgrp < 2)
        qf = *reinterpret_cast<const bf16x8*>(
            qb + ((size_t)b * L_SEQ + rowbase + w * 16 + l16) * D_KQ + h * HD_K + kgrp * 8);

    float m[4] = {-INFINITY, -INFINITY, -INFINITY, -INFINITY};
    float l[4] = {0.f, 0.f, 0.f, 0.f};
    f32x4 acc[6];
#pragma unroll
    for (int ob = 0; ob < 6; ob++) acc[ob] = (f32x4){0.f, 0.f, 0.f, 0.f};

    for (int t2 = 0; t2 <= qt; t2++) {
        const int j0 = t2 * 64;
        const bool diag = (t2 == qt);
        __syncthreads();                          // prev tile's LDS reads done

        {   // stage K: [key][0..15] = K, [16..31] = 0; thread -> (key, 4 dims)
            const int key = tid >> 2, c = (tid & 3) * 4;
            ushort4 k4 = *reinterpret_cast<const ushort4*>(
                kvbase + (size_t)(j0 + key) * D_KV + h * HD_K + c);
            *reinterpret_cast<ushort4*>(&Ks2[key * 40 + c])      = k4;
            *reinterpret_cast<ushort4*>(&Ks2[key * 40 + 16 + c]) = make_ushort4(0, 0, 0, 0);
        }
        {   // stage V transposed: thread -> (key, 24 dims)
            const int key = tid >> 2, d0 = (tid & 3) * 24;
            const uint4* vsrc = reinterpret_cast<const uint4*>(
                kvbase + (size_t)(j0 + key) * D_KV + D_KQ + h * HD_V + d0);
#pragma unroll
            for (int ch = 0; ch < 3; ch++) {
                uint4 u = vsrc[ch];
                const int d = d0 + ch * 8;
                Vt[SWZ(d + 0, key)] = (ushort)(u.x & 0xffff);
                Vt[SWZ(d + 1, key)] = (ushort)(u.x >> 16);
                Vt[SWZ(d + 2, key)] = (ushort)(u.y & 0xffff);
                Vt[SWZ(d + 3, key)] = (ushort)(u.y >> 16);
                Vt[SWZ(d + 4, key)] = (ushort)(u.z & 0xffff);
                Vt[SWZ(d + 5, key)] = (ushort)(u.z >> 16);
                Vt[SWZ(d + 6, key)] = (ushort)(u.w & 0xffff);
                Vt[SWZ(d + 7, key)] = (ushort)(u.w >> 16);
            }
        }
        __syncthreads();

        // ---- QK^T: 4 mfma (key-blocks f) ----
        f32x4 s[4];
#pragma unroll
        for (int f = 0; f < 4; f++) {
            bf16x8 kf = *reinterpret_cast<const bf16x8*>(
                &Ks2[(f * 16 + l16) * 40 + kgrp * 8]);
            s[f] = __builtin_amdgcn_mfma_f32_16x16x32_bf16(
                qf, kf, (f32x4){0.f, 0.f, 0.f, 0.f}, 0, 0, 0);
        }

        // ---- scale + causal mask (j < i strictly) ----
#pragma unroll
        for (int f = 0; f < 4; f++)
#pragma unroll
            for (int r = 0; r < 4; r++) {
                float v = s[f][r] * 0.25f;
                if (diag) {
                    const int row64 = w * 16 + kgrp * 4 + r;
                    const int key64 = f * 16 + l16;
                    if (key64 >= row64) v = -INFINITY;
                }
                s[f][r] = v;
            }

        // ---- online softmax per reg-row r ----
        float scl[4];
#pragma unroll
        for (int r = 0; r < 4; r++) {
            float mt = fmaxf(fmaxf(s[0][r], s[1][r]), fmaxf(s[2][r], s[3][r]));
            mt = fmaxf(mt, __shfl_xor(mt, 1));
            mt = fmaxf(mt, __shfl_xor(mt, 2));
            mt = fmaxf(mt, __shfl_xor(mt, 4));
            mt = fmaxf(mt, __shfl_xor(mt, 8));
            const float mn = fmaxf(m[r], mt);
            scl[r] = __expf(m[r] - mn);           // NaN only for seq row 0
            m[r] = mn;
            float ps = 0.f;
#pragma unroll
            for (int f = 0; f < 4; f++) {
                float p = __expf(s[f][r] - mn);
                s[f][r] = p;
                ps += p;
            }
            ps += __shfl_xor(ps, 1);
            ps += __shfl_xor(ps, 2);
            ps += __shfl_xor(ps, 4);
            ps += __shfl_xor(ps, 8);
            l[r] = l[r] * scl[r] + ps;
        }

        // ---- P -> bf16 -> per-wave LDS; rescale O ----
#pragma unroll
        for (int f = 0; f < 4; f++)
#pragma unroll
            for (int r = 0; r < 4; r++)
                Ps[w][SWZ(kgrp * 4 + r, f * 16 + l16)] = f2b(s[f][r]);
#pragma unroll
        for (int ob = 0; ob < 6; ob++)
#pragma unroll
            for (int r = 0; r < 4; r++)
                acc[ob][r] *= scl[r];

        asm volatile("s_waitcnt lgkmcnt(0)" ::: "memory");
        __builtin_amdgcn_sched_barrier(0);

        // ---- PV: 12 mfma ----
        bf16x8 pa0 = *reinterpret_cast<const bf16x8*>(&Ps[w][SWZ(l16, kgrp * 8)]);
        bf16x8 pa1 = *reinterpret_cast<const bf16x8*>(&Ps[w][SWZ(l16, 32 + kgrp * 8)]);
#pragma unroll
        for (int ob = 0; ob < 6; ob++) {
            bf16x8 vb0 = *reinterpret_cast<const bf16x8*>(&Vt[SWZ(ob * 16 + l16, kgrp * 8)]);
            bf16x8 vb1 = *reinterpret_cast<const bf16x8*>(&Vt[SWZ(ob * 16 + l16, 32 + kgrp * 8)]);
            acc[ob] = __builtin_amdgcn_mfma_f32_16x16x32_bf16(pa0, vb0, acc[ob], 0, 0, 0);
            acc[ob] = __builtin_amdgcn_mfma_f32_16x16x32_bf16(pa1, vb1, acc[ob], 0, 0, 0);
        }
    }

    // ---- epilogue: divide by l, write bf16 ----
#pragma unroll
    for (int r = 0; r < 4; r++) {
        const float inv = 1.f / l[r];
        ushort* dst = yb + ((size_t)b * L_SEQ + rowbase + w * 16 + kgrp * 4 + r) * D_OUT
                        + h * HD_V;
#pragma unroll
        for (int ob = 0; ob < 6; ob++)
            dst[ob * 16 + l16] = f2b(acc[ob][r] * inv);
    }
}

// ---------------------------------------------------------------------------
// first = side[:,0] @ Wemb + bemb  -> y[:, 0, :]  (bf16)
// ---------------------------------------------------------------------------
__global__ __launch_bounds__(128)
void first_kernel(const float* __restrict__ side, const float* __restrict__ Wemb,
                  const float* __restrict__ bemb, ushort* __restrict__ yb) {
    const int o = blockIdx.x * 128 + threadIdx.x;   // 0..1151
    const int b = blockIdx.y;
    const float* s = side + (size_t)b * L_SEQ * D_SIDE;
    float acc = bemb[o];
    for (int k = 0; k < D_SIDE; k++)
        acc += s[k] * Wemb[(size_t)k * D_OUT + o];
    yb[(size_t)b * L_SEQ * D_OUT + o] = f2b(acc);
}

// ---------------------------------------------------------------------------
extern "C" void kernel_launch(void* const* d_in, const int* in_sizes, int n_in,
                              void* d_out, int out_size, void* d_ws, size_t ws_size,
                              hipStream_t stream) {
    const float* x     = (const float*)d_in[0];
    const float* side  = (const float*)d_in[1];
    const float* Wq    = (const float*)d_in[2];
    const float* bq    = (const float*)d_in[3];
    const float* Wkv   = (const float*)d_in[4];
    const float* bkv   = (const float*)d_in[5];
    const float* Wproj = (const float*)d_in[6];
    const float* bproj = (const float*)d_in[7];
    const float* Wemb  = (const float*)d_in[8];
    const float* bemb  = (const float*)d_in[9];
    float* out = (float*)d_out;

    char* ws = (char*)d_ws;
    ushort* xs_bf   = (ushort*)(ws + 0);          // [4096][1152]
    ushort* side_bf = (ushort*)(ws + 9437184);    // [4096][384]
    ushort* wq_t    = (ushort*)(ws + 12582912);   // [256][384]
    ushort* wkv_t   = (ushort*)(ws + 12779520);   // [1408][1152]
    ushort* wproj_t = (ushort*)(ws + 16023552);   // [1152][1152]
    ushort* qbuf    = (ushort*)(ws + 18677760);   // [4096][192]
    ushort* kvbuf   = (ushort*)(ws + 20250624);   // [4096][1344]
    ushort* ybuf    = (ushort*)(ws + 31260672);   // [4096][1152]

    // conversions to bf16 (+ concat, + weight transposes with zero-padding)
    {
        int items_x  = (D_X / 4) * M_ROWS;      // 786432
        int items_sd = (D_SIDE / 4) * M_ROWS;   // 393216
        cvt_f32_bf16<<<(items_x  + 255) / 256, 256, 0, stream>>>(
            x,    D_X,    xs_bf,       D_OUT,  D_X / 4,    M_ROWS);
        cvt_f32_bf16<<<(items_sd + 255) / 256, 256, 0, stream>>>(
            side, D_SIDE, xs_bf + D_X, D_OUT,  D_SIDE / 4, M_ROWS);
        cvt_f32_bf16<<<(items_sd + 255) / 256, 256, 0, stream>>>(
            side, D_SIDE, side_bf,     D_SIDE, D_SIDE / 4, M_ROWS);
    }
    transpose_cvt<<<dim3(8, 12),  256, 0, stream>>>(Wq,    wq_t,    D_SIDE, D_KQ,  256);
    transpose_cvt<<<dim3(44, 36), 256, 0, stream>>>(Wkv,   wkv_t,   D_OUT,  D_KV,  1408);
    transpose_cvt<<<dim3(36, 36), 256, 0, stream>>>(Wproj, wproj_t, D_OUT,  D_OUT, 1152);

    // q = side @ Wq + bq            -> bf16 [4096][192]
    gemm_mfma<1><<<dim3(2, 32),  256, 0, stream>>>(side_bf, wq_t,    bq,    qbuf,  M_ROWS, D_KQ,  D_SIDE);
    // kv = [x,side] @ Wkv + bkv     -> bf16 [4096][1344]
    gemm_mfma<1><<<dim3(11, 32), 256, 0, stream>>>(xs_bf,   wkv_t,   bkv,   kvbuf, M_ROWS, D_KV,  D_OUT);
    // attention (MFMA flash) -> ybuf bf16
    attn_mfma<<<768, 256, 0, stream>>>(qbuf, kvbuf, ybuf);
    // first-token override (row 0 of each batch)
    first_kernel<<<dim3(9, BATCH), 128, 0, stream>>>(side, Wemb, bemb, ybuf);
    // out = y @ Wproj + bproj       -> f32
    gemm_mfma<0><<<dim3(9, 32),  256, 0, stream>>>(ybuf,    wproj_t, bproj, out,   M_ROWS, D_OUT, D_OUT);
}

// Round 6
// 280.067 us; speedup vs baseline: 6.6701x; 1.1494x over previous
//
#include <hip/hip_runtime.h>
#include <hip/hip_bf16.h>
#include <math.h>

#define N_HEADS 12
#define L_SEQ   2048
#define BATCH   2
#define D_KQ    192
#define D_OUT   1152
#define D_KV    1344   // 192 + 1152
#define D_X     768
#define D_SIDE  384
#define HD_K    16
#define HD_V    96
#define M_ROWS  4096

typedef __attribute__((ext_vector_type(8))) short bf16x8;
typedef __attribute__((ext_vector_type(4))) float f32x4;

__device__ inline float  b2f(ushort u){ union{uint i; float f;} v; v.i=(uint)u<<16; return v.f; }
__device__ inline ushort f2b(float f){ __hip_bfloat16 h = __float2bfloat16(f);
                                       return *reinterpret_cast<ushort*>(&h); }

__device__ inline void gload_lds16(const ushort* g, ushort* l) {
    __builtin_amdgcn_global_load_lds(
        (const __attribute__((address_space(1))) void*)g,
        (__attribute__((address_space(3))) void*)l, 16, 0, 0);
}

// swizzled ushort index for [R][64] bf16 LDS tiles (XOR elem bits 3..5 = byte
// bits 4..6 with row&7). Same involution used on the staging (global src) side.
#define SWZ(r, c) ((((r) * 64) + (c)) ^ (((r) & 7) << 3))

// ---------------------------------------------------------------------------
// f32 -> bf16 copy (optionally strided dest for concat). w4 = width/4.
// ---------------------------------------------------------------------------
__global__ __launch_bounds__(256)
void cvt_f32_bf16(const float* __restrict__ src, int sstride,
                  ushort* __restrict__ dst, int dstride, int w4, int rows) {
    int gid = blockIdx.x * 256 + threadIdx.x;
    if (gid >= w4 * rows) return;
    int r = gid / w4, c = gid - r * w4;
    float4 v = *reinterpret_cast<const float4*>(&src[(size_t)r * sstride + c * 4]);
    ushort4 o = make_ushort4(f2b(v.x), f2b(v.y), f2b(v.z), f2b(v.w));
    *reinterpret_cast<ushort4*>(&dst[(size_t)r * dstride + c * 4]) = o;
}

// ---------------------------------------------------------------------------
// W[K][N] f32  ->  Wt[Npad][K] bf16 (rows >= N zero-filled). K%32==0, N%32==0.
// ---------------------------------------------------------------------------
__global__ __launch_bounds__(256)
void transpose_cvt(const float* __restrict__ W, ushort* __restrict__ Wt,
                   int K, int N, int Npad) {
    __shared__ float t[32][33];
    const int n0 = blockIdx.x * 32, k0 = blockIdx.y * 32;
    const int tx = threadIdx.x & 31, ty = threadIdx.x >> 5;   // ty 0..7
#pragma unroll
    for (int i = 0; i < 4; i++) {
        int n = n0 + tx;
        t[ty + i * 8][tx] = (n < N) ? W[(size_t)(k0 + ty + i * 8) * N + n] : 0.f;
    }
    __syncthreads();
#pragma unroll
    for (int i = 0; i < 4; i++) {
        int n = n0 + ty + i * 8;
        Wt[(size_t)n * K + k0 + tx] = f2b(t[tx][ty + i * 8]);
    }
}

// ---------------------------------------------------------------------------
// bf16 MFMA GEMM: C[M,N] = A[M,K] @ Wt[N,K]^T + bias.  128x128 tile, BK=32,
// 4 waves x (64x64), 16x16x32 MFMA, global_load_lds(16) staging.
// MODE 0: f32 C.  MODE 1: bf16 C.  MODE 2: split-kv epilogue —
//   col<192 -> kbuf(Cv)[row][192] bf16;  col>=192 -> vt[b][h][d][row] bf16.
// ---------------------------------------------------------------------------
template<int MODE>
__global__ __launch_bounds__(256)
void gemm_mfma(const ushort* __restrict__ A, const ushort* __restrict__ Bt,
               const float* __restrict__ bias, void* __restrict__ Cv,
               ushort* __restrict__ vt, int M, int N, int K) {
    __shared__ ushort As[128 * 32];
    __shared__ ushort Bs[128 * 32];
    const int tid = threadIdx.x;
    const int w = tid >> 6, lane = tid & 63;
    const int wr = w >> 1, wc = w & 1;
    const int n0 = blockIdx.x * 128, m0 = blockIdx.y * 128;
    const int l4 = lane & 3, lrow = lane >> 2;
    const int kgrp = lane >> 4, l16 = lane & 15;

    f32x4 acc[4][4];
#pragma unroll
    for (int i = 0; i < 4; i++)
#pragma unroll
        for (int j = 0; j < 4; j++)
            acc[i][j] = (f32x4){0.f, 0.f, 0.f, 0.f};

    for (int kt = 0; kt < K; kt += 32) {
        __syncthreads();
#pragma unroll
        for (int r = 0; r < 2; r++) {
            const int seg = r * 4 + w;              // 0..7, wave-uniform
            const int trow = seg * 16 + lrow;       // tile row this lane loads
            gload_lds16(&A [(size_t)(m0 + trow) * K + kt + l4 * 8], &As[seg * 512]);
            gload_lds16(&Bt[(size_t)(n0 + trow) * K + kt + l4 * 8], &Bs[seg * 512]);
        }
        __syncthreads();

        bf16x8 a[4], b[4];
#pragma unroll
        for (int i = 0; i < 4; i++)
            a[i] = *reinterpret_cast<const bf16x8*>(
                &As[(wr * 64 + i * 16 + l16) * 32 + kgrp * 8]);
#pragma unroll
        for (int j = 0; j < 4; j++)
            b[j] = *reinterpret_cast<const bf16x8*>(
                &Bs[(wc * 64 + j * 16 + l16) * 32 + kgrp * 8]);
#pragma unroll
        for (int i = 0; i < 4; i++)
#pragma unroll
            for (int j = 0; j < 4; j++)
                acc[i][j] = __builtin_amdgcn_mfma_f32_16x16x32_bf16(
                    a[i], b[j], acc[i][j], 0, 0, 0);
    }

    const int rgrp = lane >> 4;
#pragma unroll
    for (int j = 0; j < 4; j++) {
        const int col = n0 + wc * 64 + j * 16 + l16;
        if (col >= N) continue;
        const float bv = bias[col];
        if constexpr (MODE == 2) {
            if (col >= D_KQ) {
                // V column: write transposed to vt[b][h][d][row]
                const int hh = (col - D_KQ) / HD_V;
                const int dd = (col - D_KQ) % HD_V;
                const int bb = m0 >> 11;             // 2048 % 128 == 0
                ushort* vrow = vt + ((size_t)(bb * N_HEADS + hh) * HD_V + dd) * L_SEQ
                                  + (m0 & 2047);
#pragma unroll
                for (int i = 0; i < 4; i++) {
                    const int r0 = wr * 64 + i * 16 + rgrp * 4;
                    ushort4 o = make_ushort4(
                        f2b(acc[i][j][0] + bv), f2b(acc[i][j][1] + bv),
                        f2b(acc[i][j][2] + bv), f2b(acc[i][j][3] + bv));
                    *reinterpret_cast<ushort4*>(&vrow[r0]) = o;
                }
                continue;
            }
            // K column: bf16 to kbuf [row][192]
#pragma unroll
            for (int i = 0; i < 4; i++) {
                const int row0 = m0 + wr * 64 + i * 16 + rgrp * 4;
#pragma unroll
                for (int rg = 0; rg < 4; rg++)
                    ((ushort*)Cv)[(size_t)(row0 + rg) * D_KQ + col] =
                        f2b(acc[i][j][rg] + bv);
            }
            continue;
        }
#pragma unroll
        for (int i = 0; i < 4; i++) {
            const int row0 = m0 + wr * 64 + i * 16 + rgrp * 4;
#pragma unroll
            for (int rg = 0; rg < 4; rg++) {
                float v = acc[i][j][rg] + bv;
                if (MODE == 1)
                    ((ushort*)Cv)[(size_t)(row0 + rg) * N + col] = f2b(v);
                else
                    ((float*)Cv)[(size_t)(row0 + rg) * N + col] = v;
            }
        }
    }
}

// ---------------------------------------------------------------------------
// MFMA flash attention. One block = 64 q-rows x 1 head; 4 waves, wave w owns
// q-rows [w*16, w*16+16). All staging via global_load_lds (V pre-transposed
// in global, read swizzle carried by the per-lane global source address).
// Balanced static qt mapping: per-CU triples {q, 31-q, (q+16)&31}.
// Row 0 of the sequence produces NaN (l=0); first_kernel overwrites it.
// ---------------------------------------------------------------------------
__global__ __launch_bounds__(256)
void attn_mfma(const ushort* __restrict__ qbuf, const ushort* __restrict__ kb,
               const ushort* __restrict__ vtg, ushort* __restrict__ yb) {
    __shared__ ushort Vt[96 * 64];          // 12 KB swizzled [dim][key]
    __shared__ ushort Ks[64 * 16];          //  2 KB linear [key][16]
    __shared__ __align__(16) ushort Kz[8];  // zeros for k-pad reads
    __shared__ ushort Ps[4][16 * 64];       //  8 KB per-wave P, swizzled

    const int tid = threadIdx.x;
    const int w = tid >> 6, lane = tid & 63;
    const int l16 = lane & 15, kgrp = lane >> 4;

    // balanced static mapping: blocks i, i+256, i+512 -> qt {q, 31-q, (q+16)&31}
    const int i = blockIdx.x, jj5 = i & 255, g = i >> 8;
    const int q5 = jj5 & 31;
    const int qt = (g == 0) ? q5 : (g == 1) ? (31 - q5) : ((q5 + 16) & 31);
    const int hb = g * 8 + (jj5 >> 5);      // 0..23
    const int h = hb % N_HEADS, b = hb / N_HEADS;

    if (tid < 8) Kz[tid] = 0;

    const ushort* vt_h  = vtg + (size_t)(b * N_HEADS + h) * HD_V * L_SEQ;
    const ushort* kbase = kb + (size_t)b * L_SEQ * D_KQ;
    const int rowbase = qt * 64;

    // per-lane staging offsets (precomputed, add j0 per tile)
    int voff[3];
#pragma unroll
    for (int s3 = 0; s3 < 3; s3++) {
        const int L = (w * 3 + s3) * 1024 + lane * 16;     // LDS byte
        const int X = L ^ (((L >> 7) & 7) << 4);           // logical byte
        voff[s3] = (X >> 7) * L_SEQ + ((X >> 1) & 63);     // dim*2048 + key
    }
    int koff = 0;
    if (w < 2) {
        const int elem = (w * 1024 + lane * 16) >> 1;
        koff = (elem >> 4) * D_KQ + h * HD_K + ((elem >> 3) & 1) * 8;
    }

    // Q fragment (constant across tiles)
    bf16x8 qf = {0, 0, 0, 0, 0, 0, 0, 0};
    if (kgrp < 2)
        qf = *reinterpret_cast<const bf16x8*>(
            qbuf + ((size_t)b * L_SEQ + rowbase + w * 16 + l16) * D_KQ
                 + h * HD_K + kgrp * 8);

    float m[4] = {-INFINITY, -INFINITY, -INFINITY, -INFINITY};
    float l[4] = {0.f, 0.f, 0.f, 0.f};
    f32x4 acc[6];
#pragma unroll
    for (int ob = 0; ob < 6; ob++) acc[ob] = (f32x4){0.f, 0.f, 0.f, 0.f};

    for (int t2 = 0; t2 <= qt; t2++) {
        const int j0 = t2 * 64;
        const bool diag = (t2 == qt);
        __syncthreads();                    // prev tile's LDS reads done

        // ---- stage K (2 wave-instrs) + Vt (12 wave-instrs) ----
        if (w < 2)
            gload_lds16(kbase + (size_t)j0 * D_KQ + koff, &Ks[w * 512]);
#pragma unroll
        for (int s3 = 0; s3 < 3; s3++)
            gload_lds16(vt_h + voff[s3] + j0, &Vt[(w * 3 + s3) * 512]);
        __syncthreads();                    // drains vmcnt -> LDS ready

        // ---- QK^T: 4 mfma ----
        __builtin_amdgcn_s_setprio(1);
        f32x4 s[4];
#pragma unroll
        for (int f = 0; f < 4; f++) {
            const ushort* kp = (kgrp < 2) ? &Ks[(f * 16 + l16) * 16 + kgrp * 8]
                                          : &Kz[0];
            bf16x8 kf = *reinterpret_cast<const bf16x8*>(kp);
            s[f] = __builtin_amdgcn_mfma_f32_16x16x32_bf16(
                qf, kf, (f32x4){0.f, 0.f, 0.f, 0.f}, 0, 0, 0);
        }
        __builtin_amdgcn_s_setprio(0);

        // ---- scale + causal mask (j < i strictly) ----
#pragma unroll
        for (int f = 0; f < 4; f++)
#pragma unroll
            for (int r = 0; r < 4; r++) {
                float v = s[f][r] * 0.25f;
                if (diag) {
                    const int row64 = w * 16 + kgrp * 4 + r;
                    const int key64 = f * 16 + l16;
                    if (key64 >= row64) v = -INFINITY;
                }
                s[f][r] = v;
            }

        // ---- online softmax per reg-row r ----
        float scl[4];
#pragma unroll
        for (int r = 0; r < 4; r++) {
            float mt = fmaxf(fmaxf(s[0][r], s[1][r]), fmaxf(s[2][r], s[3][r]));
            mt = fmaxf(mt, __shfl_xor(mt, 1));
            mt = fmaxf(mt, __shfl_xor(mt, 2));
            mt = fmaxf(mt, __shfl_xor(mt, 4));
            mt = fmaxf(mt, __shfl_xor(mt, 8));
            const float mn = fmaxf(m[r], mt);
            scl[r] = __expf(m[r] - mn);     // NaN only for seq row 0
            m[r] = mn;
            float ps = 0.f;
#pragma unroll
            for (int f = 0; f < 4; f++) {
                float p = __expf(s[f][r] - mn);
                s[f][r] = p;
                ps += p;
            }
            ps += __shfl_xor(ps, 1);
            ps += __shfl_xor(ps, 2);
            ps += __shfl_xor(ps, 4);
            ps += __shfl_xor(ps, 8);
            l[r] = l[r] * scl[r] + ps;
        }

        // ---- P -> bf16 -> per-wave LDS; rescale O ----
#pragma unroll
        for (int f = 0; f < 4; f++)
#pragma unroll
            for (int r = 0; r < 4; r++)
                Ps[w][SWZ(kgrp * 4 + r, f * 16 + l16)] = f2b(s[f][r]);
#pragma unroll
        for (int ob = 0; ob < 6; ob++)
#pragma unroll
            for (int r = 0; r < 4; r++)
                acc[ob][r] *= scl[r];

        asm volatile("s_waitcnt lgkmcnt(0)" ::: "memory");
        __builtin_amdgcn_sched_barrier(0);

        // ---- PV: 12 mfma ----
        bf16x8 pa0 = *reinterpret_cast<const bf16x8*>(&Ps[w][SWZ(l16, kgrp * 8)]);
        bf16x8 pa1 = *reinterpret_cast<const bf16x8*>(&Ps[w][SWZ(l16, 32 + kgrp * 8)]);
        __builtin_amdgcn_s_setprio(1);
#pragma unroll
        for (int ob = 0; ob < 6; ob++) {
            bf16x8 vb0 = *reinterpret_cast<const bf16x8*>(&Vt[SWZ(ob * 16 + l16, kgrp * 8)]);
            bf16x8 vb1 = *reinterpret_cast<const bf16x8*>(&Vt[SWZ(ob * 16 + l16, 32 + kgrp * 8)]);
            acc[ob] = __builtin_amdgcn_mfma_f32_16x16x32_bf16(pa0, vb0, acc[ob], 0, 0, 0);
            acc[ob] = __builtin_amdgcn_mfma_f32_16x16x32_bf16(pa1, vb1, acc[ob], 0, 0, 0);
        }
        __builtin_amdgcn_s_setprio(0);
    }

    // ---- epilogue: divide by l, write bf16 ----
#pragma unroll
    for (int r = 0; r < 4; r++) {
        const float inv = 1.f / l[r];
        ushort* dst = yb + ((size_t)b * L_SEQ + rowbase + w * 16 + kgrp * 4 + r) * D_OUT
                        + h * HD_V;
#pragma unroll
        for (int ob = 0; ob < 6; ob++)
            dst[ob * 16 + l16] = f2b(acc[ob][r] * inv);
    }
}

// ---------------------------------------------------------------------------
// first = side[:,0] @ Wemb + bemb  -> y[:, 0, :]  (bf16)
// ---------------------------------------------------------------------------
__global__ __launch_bounds__(128)
void first_kernel(const float* __restrict__ side, const float* __restrict__ Wemb,
                  const float* __restrict__ bemb, ushort* __restrict__ yb) {
    const int o = blockIdx.x * 128 + threadIdx.x;   // 0..1151
    const int b = blockIdx.y;
    const float* s = side + (size_t)b * L_SEQ * D_SIDE;
    float acc = bemb[o];
    for (int k = 0; k < D_SIDE; k++)
        acc += s[k] * Wemb[(size_t)k * D_OUT + o];
    yb[(size_t)b * L_SEQ * D_OUT + o] = f2b(acc);
}

// ---------------------------------------------------------------------------
extern "C" void kernel_launch(void* const* d_in, const int* in_sizes, int n_in,
                              void* d_out, int out_size, void* d_ws, size_t ws_size,
                              hipStream_t stream) {
    const float* x     = (const float*)d_in[0];
    const float* side  = (const float*)d_in[1];
    const float* Wq    = (const float*)d_in[2];
    const float* bq    = (const float*)d_in[3];
    const float* Wkv   = (const float*)d_in[4];
    const float* bkv   = (const float*)d_in[5];
    const float* Wproj = (const float*)d_in[6];
    const float* bproj = (const float*)d_in[7];
    const float* Wemb  = (const float*)d_in[8];
    const float* bemb  = (const float*)d_in[9];
    float* out = (float*)d_out;

    char* ws = (char*)d_ws;
    ushort* xs_bf   = (ushort*)(ws + 0);          // [4096][1152]
    ushort* side_bf = (ushort*)(ws + 9437184);    // [4096][384]
    ushort* wq_t    = (ushort*)(ws + 12582912);   // [256][384]
    ushort* wkv_t   = (ushort*)(ws + 12779520);   // [1408][1152]
    ushort* wproj_t = (ushort*)(ws + 16023552);   // [1152][1152]
    ushort* qbuf    = (ushort*)(ws + 18677760);   // [4096][192]
    ushort* kbuf    = (ushort*)(ws + 20250624);   // [4096][192]
    ushort* vtg     = (ushort*)(ws + 21823488);   // [24][96][2048]
    ushort* ybuf    = (ushort*)(ws + 31260672);   // [4096][1152]

    // conversions to bf16 (+ concat, + weight transposes with zero-padding)
    {
        int items_x  = (D_X / 4) * M_ROWS;      // 786432
        int items_sd = (D_SIDE / 4) * M_ROWS;   // 393216
        cvt_f32_bf16<<<(items_x  + 255) / 256, 256, 0, stream>>>(
            x,    D_X,    xs_bf,       D_OUT,  D_X / 4,    M_ROWS);
        cvt_f32_bf16<<<(items_sd + 255) / 256, 256, 0, stream>>>(
            side, D_SIDE, xs_bf + D_X, D_OUT,  D_SIDE / 4, M_ROWS);
        cvt_f32_bf16<<<(items_sd + 255) / 256, 256, 0, stream>>>(
            side, D_SIDE, side_bf,     D_SIDE, D_SIDE / 4, M_ROWS);
    }
    transpose_cvt<<<dim3(8, 12),  256, 0, stream>>>(Wq,    wq_t,    D_SIDE, D_KQ,  256);
    transpose_cvt<<<dim3(44, 36), 256, 0, stream>>>(Wkv,   wkv_t,   D_OUT,  D_KV,  1408);
    transpose_cvt<<<dim3(36, 36), 256, 0, stream>>>(Wproj, wproj_t, D_OUT,  D_OUT, 1152);

    // q = side @ Wq + bq            -> bf16 [4096][192]
    gemm_mfma<1><<<dim3(2, 32),  256, 0, stream>>>(
        side_bf, wq_t, bq, qbuf, nullptr, M_ROWS, D_KQ, D_SIDE);
    // kv = [x,side] @ Wkv + bkv     -> K to kbuf, V transposed to vtg
    gemm_mfma<2><<<dim3(11, 32), 256, 0, stream>>>(
        xs_bf, wkv_t, bkv, kbuf, vtg, M_ROWS, D_KV, D_OUT);
    // attention (MFMA flash) -> ybuf bf16
    attn_mfma<<<768, 256, 0, stream>>>(qbuf, kbuf, vtg, ybuf);
    // first-token override (row 0 of each batch)
    first_kernel<<<dim3(9, BATCH), 128, 0, stream>>>(side, Wemb, bemb, ybuf);
    // out = y @ Wproj + bproj       -> f32
    gemm_mfma<0><<<dim3(9, 32),  256, 0, stream>>>(
        ybuf, wproj_t, bproj, out, nullptr, M_ROWS, D_OUT, D_OUT);
}

// Round 7
// 259.017 us; speedup vs baseline: 7.2121x; 1.0813x over previous
//
#include <hip/hip_runtime.h>
#include <hip/hip_bf16.h>
#include <math.h>

#define N_HEADS 12
#define L_SEQ   2048
#define BATCH   2
#define D_KQ    192
#define D_OUT   1152
#define D_KV    1344   // 192 + 1152
#define D_KVQ   1536   // 192 + 1152 + 192 (fused q columns)
#define D_X     768
#define D_SIDE  384
#define HD_K    16
#define HD_V    96
#define M_ROWS  4096

typedef __attribute__((ext_vector_type(8))) short bf16x8;
typedef __attribute__((ext_vector_type(4))) float f32x4;

__device__ inline ushort f2b(float f){ __hip_bfloat16 h = __float2bfloat16(f);
                                       return *reinterpret_cast<ushort*>(&h); }

__device__ inline void gload_lds16(const ushort* g, ushort* l) {
    __builtin_amdgcn_global_load_lds(
        (const __attribute__((address_space(1))) void*)g,
        (__attribute__((address_space(3))) void*)l, 16, 0, 0);
}

// swizzled ushort index for [R][64] bf16 LDS tiles (XOR elem bits 3..5 = byte
// bits 4..6 with row&7). Same involution applied to the staging source address.
#define SWZ(r, c) ((((r) * 64) + (c)) ^ (((r) & 7) << 3))

// ---------------------------------------------------------------------------
// Input prep: xs_bf[4096][1152] = bf16(concat(x, side)) in one launch.
// ---------------------------------------------------------------------------
__global__ __launch_bounds__(256)
void cvt_inputs(const float* __restrict__ x, const float* __restrict__ side,
                ushort* __restrict__ xs_bf) {
    const int gid = blockIdx.x * 256 + threadIdx.x;
    if (gid < 786432) {                       // x part: 192 float4 per row
        const int r = gid / 192, c = (gid - r * 192) * 4;
        float4 v = *reinterpret_cast<const float4*>(&x[(size_t)r * D_X + c]);
        ushort4 o = make_ushort4(f2b(v.x), f2b(v.y), f2b(v.z), f2b(v.w));
        *reinterpret_cast<ushort4*>(&xs_bf[(size_t)r * D_OUT + c]) = o;
    } else {                                  // side part: 96 float4 per row
        const int g2 = gid - 786432;
        const int r = g2 / 96, c = (g2 - r * 96) * 4;
        float4 v = *reinterpret_cast<const float4*>(&side[(size_t)r * D_SIDE + c]);
        ushort4 o = make_ushort4(f2b(v.x), f2b(v.y), f2b(v.z), f2b(v.w));
        *reinterpret_cast<ushort4*>(&xs_bf[(size_t)r * D_OUT + D_X + c]) = o;
    }
}

// ---------------------------------------------------------------------------
// Fused kvq weight transpose: virtual W2[1152][1536] = [Wkv | [0;Wq]]
//   -> wt[1536][1152] bf16.  Grid (48, 36).
// ---------------------------------------------------------------------------
__global__ __launch_bounds__(256)
void transpose_kvq(const float* __restrict__ Wkv, const float* __restrict__ Wq,
                   ushort* __restrict__ Wt) {
    __shared__ float t[32][33];
    const int n0 = blockIdx.x * 32, k0 = blockIdx.y * 32;
    const int tx = threadIdx.x & 31, ty = threadIdx.x >> 5;   // ty 0..7
#pragma unroll
    for (int i = 0; i < 4; i++) {
        const int k = k0 + ty + i * 8, n = n0 + tx;
        float v;
        if (n < D_KV)        v = Wkv[(size_t)k * D_KV + n];
        else if (k >= D_X)   v = Wq[(size_t)(k - D_X) * D_KQ + (n - D_KV)];
        else                 v = 0.f;
        t[ty + i * 8][tx] = v;
    }
    __syncthreads();
#pragma unroll
    for (int i = 0; i < 4; i++) {
        const int n = n0 + ty + i * 8;
        Wt[(size_t)n * D_OUT + k0 + tx] = f2b(t[tx][ty + i * 8]);
    }
}

// ---------------------------------------------------------------------------
// W[K][N] f32 -> Wt[N][K] bf16 (square, in-bounds). Grid (N/32, K/32).
// ---------------------------------------------------------------------------
__global__ __launch_bounds__(256)
void transpose_cvt(const float* __restrict__ W, ushort* __restrict__ Wt,
                   int K, int N) {
    __shared__ float t[32][33];
    const int n0 = blockIdx.x * 32, k0 = blockIdx.y * 32;
    const int tx = threadIdx.x & 31, ty = threadIdx.x >> 5;
#pragma unroll
    for (int i = 0; i < 4; i++)
        t[ty + i * 8][tx] = W[(size_t)(k0 + ty + i * 8) * N + n0 + tx];
    __syncthreads();
#pragma unroll
    for (int i = 0; i < 4; i++) {
        const int n = n0 + ty + i * 8;
        Wt[(size_t)n * K + k0 + tx] = f2b(t[tx][ty + i * 8]);
    }
}

// ---------------------------------------------------------------------------
// bf16 MFMA GEMM: C[M,N] = A[M,K] @ Wt[N,K]^T + bias.  128x128 tile, BK=32,
// 4 waves x (64x64), 16x16x32 MFMA, global_load_lds(16) staging.
// MODE 0: f32 C.  MODE 2: fused kvq epilogue —
//   col<192: K -> Cv[row][192] bf16;  192..1343: V -> vt[b][h][d][row];
//   >=1344: Q -> qout[row][192] bf16 (bias from bias2).
// ---------------------------------------------------------------------------
template<int MODE>
__global__ __launch_bounds__(256)
void gemm_mfma(const ushort* __restrict__ A, const ushort* __restrict__ Bt,
               const float* __restrict__ bias, const float* __restrict__ bias2,
               void* __restrict__ Cv, ushort* __restrict__ vt,
               ushort* __restrict__ qout, int M, int N, int K) {
    __shared__ ushort As[128 * 32];
    __shared__ ushort Bs[128 * 32];
    const int tid = threadIdx.x;
    const int w = tid >> 6, lane = tid & 63;
    const int wr = w >> 1, wc = w & 1;
    const int n0 = blockIdx.x * 128, m0 = blockIdx.y * 128;
    const int l4 = lane & 3, lrow = lane >> 2;
    const int kgrp = lane >> 4, l16 = lane & 15;

    f32x4 acc[4][4];
#pragma unroll
    for (int i = 0; i < 4; i++)
#pragma unroll
        for (int j = 0; j < 4; j++)
            acc[i][j] = (f32x4){0.f, 0.f, 0.f, 0.f};

    for (int kt = 0; kt < K; kt += 32) {
        __syncthreads();
#pragma unroll
        for (int r = 0; r < 2; r++) {
            const int seg = r * 4 + w;              // 0..7, wave-uniform
            const int trow = seg * 16 + lrow;
            gload_lds16(&A [(size_t)(m0 + trow) * K + kt + l4 * 8], &As[seg * 512]);
            gload_lds16(&Bt[(size_t)(n0 + trow) * K + kt + l4 * 8], &Bs[seg * 512]);
        }
        __syncthreads();

        bf16x8 a[4], b[4];
#pragma unroll
        for (int i = 0; i < 4; i++)
            a[i] = *reinterpret_cast<const bf16x8*>(
                &As[(wr * 64 + i * 16 + l16) * 32 + kgrp * 8]);
#pragma unroll
        for (int j = 0; j < 4; j++)
            b[j] = *reinterpret_cast<const bf16x8*>(
                &Bs[(wc * 64 + j * 16 + l16) * 32 + kgrp * 8]);
#pragma unroll
        for (int i = 0; i < 4; i++)
#pragma unroll
            for (int j = 0; j < 4; j++)
                acc[i][j] = __builtin_amdgcn_mfma_f32_16x16x32_bf16(
                    a[i], b[j], acc[i][j], 0, 0, 0);
    }

    const int rgrp = lane >> 4;
#pragma unroll
    for (int j = 0; j < 4; j++) {
        const int col = n0 + wc * 64 + j * 16 + l16;
        if constexpr (MODE == 2) {
            if (col < D_KQ) {                       // K column
                const float bv = bias[col];
#pragma unroll
                for (int i = 0; i < 4; i++) {
                    const int row0 = m0 + wr * 64 + i * 16 + rgrp * 4;
#pragma unroll
                    for (int rg = 0; rg < 4; rg++)
                        ((ushort*)Cv)[(size_t)(row0 + rg) * D_KQ + col] =
                            f2b(acc[i][j][rg] + bv);
                }
            } else if (col < D_KV) {                // V column -> transposed
                const float bv = bias[col];
                const int hh = (col - D_KQ) / HD_V;
                const int dd = (col - D_KQ) % HD_V;
                const int bb = m0 >> 11;
                ushort* vrow = vt + ((size_t)(bb * N_HEADS + hh) * HD_V + dd) * L_SEQ
                                  + (m0 & 2047);
#pragma unroll
                for (int i = 0; i < 4; i++) {
                    const int r0 = wr * 64 + i * 16 + rgrp * 4;
                    ushort4 o = make_ushort4(
                        f2b(acc[i][j][0] + bv), f2b(acc[i][j][1] + bv),
                        f2b(acc[i][j][2] + bv), f2b(acc[i][j][3] + bv));
                    *reinterpret_cast<ushort4*>(&vrow[r0]) = o;
                }
            } else {                                // Q column
                const int qc = col - D_KV;
                const float bv = bias2[qc];
#pragma unroll
                for (int i = 0; i < 4; i++) {
                    const int row0 = m0 + wr * 64 + i * 16 + rgrp * 4;
#pragma unroll
                    for (int rg = 0; rg < 4; rg++)
                        qout[(size_t)(row0 + rg) * D_KQ + qc] =
                            f2b(acc[i][j][rg] + bv);
                }
            }
            continue;
        }
        if (col >= N) continue;
        const float bv = bias[col];
#pragma unroll
        for (int i = 0; i < 4; i++) {
            const int row0 = m0 + wr * 64 + i * 16 + rgrp * 4;
#pragma unroll
            for (int rg = 0; rg < 4; rg++)
                ((float*)Cv)[(size_t)(row0 + rg) * N + col] = acc[i][j][rg] + bv;
        }
    }
}

// ---------------------------------------------------------------------------
// MFMA flash attention. One block = 32 q-rows x 1 head; 2 waves, wave w owns
// q-rows [w*16, w*16+16). Grid 1536; CU-pair mapping t <-> 63-t gives every
// CU exactly 99 key-tile units. Staging via global_load_lds (V pre-transposed
// in global, read swizzle carried by the per-lane source address).
// Seq row 0 produces NaN (l=0); first_kernel overwrites it afterwards.
// ---------------------------------------------------------------------------
__global__ __launch_bounds__(128)
void attn_mfma(const ushort* __restrict__ qbuf, const ushort* __restrict__ kb,
               const ushort* __restrict__ vtg, ushort* __restrict__ yb) {
    __shared__ ushort Vt[96 * 64];          // 12 KB swizzled [dim][key]
    __shared__ ushort Ks[64 * 16];          //  2 KB linear [key][16]
    __shared__ __align__(16) ushort Kz[8];  // zeros for k-pad fragment
    __shared__ ushort Ps[2][16 * 64];       //  4 KB per-wave P, swizzled

    const int tid = threadIdx.x;
    const int w = tid >> 6, lane = tid & 63;
    const int l16 = lane & 15, kgrp = lane >> 4;

    // balanced mapping: i -> (t, hb); blocks c, c+256, ... alternate t / 63-t
    const int i = blockIdx.x, j5 = i & 255, g = i >> 8;         // g 0..5
    const int tb = j5 & 63;
    const int t  = (g & 1) ? (63 - tb) : tb;                    // q-tile 0..63
    const int hb = (g << 2) | (j5 >> 6);                        // 0..23
    const int h = hb % N_HEADS, b = hb / N_HEADS;

    if (tid < 8) Kz[tid] = 0;

    const ushort* vt_h  = vtg + (size_t)(b * N_HEADS + h) * HD_V * L_SEQ;
    const ushort* kbase = kb + (size_t)b * L_SEQ * D_KQ;
    const int rowbase = t * 32;
    const int nt = (t >> 1) + 1;            // 64-key tiles needed
    const int rowoff = (t & 1) * 32;        // diag-tile row offset

    // per-lane staging offsets (inverse-swizzled global source)
    int voff[6];
#pragma unroll
    for (int s6 = 0; s6 < 6; s6++) {
        const int L = (w * 6 + s6) * 1024 + lane * 16;     // LDS byte
        const int X = L ^ (((L >> 7) & 7) << 4);           // logical byte
        voff[s6] = (X >> 7) * L_SEQ + ((X >> 1) & 63);     // dim*2048 + key
    }
    int koff;
    {
        const int elem = (w * 1024 + lane * 16) >> 1;
        koff = (elem >> 4) * D_KQ + h * HD_K + ((elem >> 3) & 1) * 8;
    }

    // Q fragment (constant across tiles)
    bf16x8 qf = {0, 0, 0, 0, 0, 0, 0, 0};
    if (kgrp < 2)
        qf = *reinterpret_cast<const bf16x8*>(
            qbuf + ((size_t)b * L_SEQ + rowbase + w * 16 + l16) * D_KQ
                 + h * HD_K + kgrp * 8);

    float m[4] = {-INFINITY, -INFINITY, -INFINITY, -INFINITY};
    float l[4] = {0.f, 0.f, 0.f, 0.f};
    f32x4 acc[6];
#pragma unroll
    for (int ob = 0; ob < 6; ob++) acc[ob] = (f32x4){0.f, 0.f, 0.f, 0.f};

    for (int t2 = 0; t2 < nt; t2++) {
        const int j0 = t2 * 64;
        const bool diag = (t2 == nt - 1);
        __syncthreads();                    // prev tile's LDS reads done

        // ---- stage K (1 instr/wave) + Vt (6 instrs/wave) ----
        gload_lds16(kbase + (size_t)j0 * D_KQ + koff, &Ks[w * 512]);
#pragma unroll
        for (int s6 = 0; s6 < 6; s6++)
            gload_lds16(vt_h + voff[s6] + j0, &Vt[(w * 6 + s6) * 512]);
        __syncthreads();                    // drains vmcnt -> LDS ready

        // ---- QK^T: 4 mfma ----
        __builtin_amdgcn_s_setprio(1);
        f32x4 s[4];
#pragma unroll
        for (int f = 0; f < 4; f++) {
            const ushort* kp = (kgrp < 2) ? &Ks[(f * 16 + l16) * 16 + kgrp * 8]
                                          : &Kz[0];
            bf16x8 kf = *reinterpret_cast<const bf16x8*>(kp);
            s[f] = __builtin_amdgcn_mfma_f32_16x16x32_bf16(
                qf, kf, (f32x4){0.f, 0.f, 0.f, 0.f}, 0, 0, 0);
        }
        __builtin_amdgcn_s_setprio(0);

        // ---- scale + causal mask (key_abs < row_abs) ----
#pragma unroll
        for (int f = 0; f < 4; f++)
#pragma unroll
            for (int r = 0; r < 4; r++) {
                float v = s[f][r] * 0.25f;
                if (diag) {
                    const int row32 = w * 16 + kgrp * 4 + r;
                    const int key64 = f * 16 + l16;
                    if (key64 >= rowoff + row32) v = -INFINITY;
                }
                s[f][r] = v;
            }

        // ---- online softmax per reg-row r ----
        float scl[4];
#pragma unroll
        for (int r = 0; r < 4; r++) {
            float mt = fmaxf(fmaxf(s[0][r], s[1][r]), fmaxf(s[2][r], s[3][r]));
            mt = fmaxf(mt, __shfl_xor(mt, 1));
            mt = fmaxf(mt, __shfl_xor(mt, 2));
            mt = fmaxf(mt, __shfl_xor(mt, 4));
            mt = fmaxf(mt, __shfl_xor(mt, 8));
            const float mn = fmaxf(m[r], mt);
            scl[r] = __expf(m[r] - mn);     // NaN only for seq row 0
            m[r] = mn;
            float ps = 0.f;
#pragma unroll
            for (int f = 0; f < 4; f++) {
                float p = __expf(s[f][r] - mn);
                s[f][r] = p;
                ps += p;
            }
            ps += __shfl_xor(ps, 1);
            ps += __shfl_xor(ps, 2);
            ps += __shfl_xor(ps, 4);
            ps += __shfl_xor(ps, 8);
            l[r] = l[r] * scl[r] + ps;
        }

        // ---- P -> bf16 -> per-wave LDS; rescale O ----
#pragma unroll
        for (int f = 0; f < 4; f++)
#pragma unroll
            for (int r = 0; r < 4; r++)
                Ps[w][SWZ(kgrp * 4 + r, f * 16 + l16)] = f2b(s[f][r]);
#pragma unroll
        for (int ob = 0; ob < 6; ob++)
#pragma unroll
            for (int r = 0; r < 4; r++)
                acc[ob][r] *= scl[r];

        asm volatile("s_waitcnt lgkmcnt(0)" ::: "memory");
        __builtin_amdgcn_sched_barrier(0);

        // ---- PV: 12 mfma ----
        bf16x8 pa0 = *reinterpret_cast<const bf16x8*>(&Ps[w][SWZ(l16, kgrp * 8)]);
        bf16x8 pa1 = *reinterpret_cast<const bf16x8*>(&Ps[w][SWZ(l16, 32 + kgrp * 8)]);
        __builtin_amdgcn_s_setprio(1);
#pragma unroll
        for (int ob = 0; ob < 6; ob++) {
            bf16x8 vb0 = *reinterpret_cast<const bf16x8*>(&Vt[SWZ(ob * 16 + l16, kgrp * 8)]);
            bf16x8 vb1 = *reinterpret_cast<const bf16x8*>(&Vt[SWZ(ob * 16 + l16, 32 + kgrp * 8)]);
            acc[ob] = __builtin_amdgcn_mfma_f32_16x16x32_bf16(pa0, vb0, acc[ob], 0, 0, 0);
            acc[ob] = __builtin_amdgcn_mfma_f32_16x16x32_bf16(pa1, vb1, acc[ob], 0, 0, 0);
        }
        __builtin_amdgcn_s_setprio(0);
    }

    // ---- epilogue: divide by l, write bf16 ----
#pragma unroll
    for (int r = 0; r < 4; r++) {
        const float inv = 1.f / l[r];
        ushort* dst = yb + ((size_t)b * L_SEQ + rowbase + w * 16 + kgrp * 4 + r) * D_OUT
                        + h * HD_V;
#pragma unroll
        for (int ob = 0; ob < 6; ob++)
            dst[ob * 16 + l16] = f2b(acc[ob][r] * inv);
    }
}

// ---------------------------------------------------------------------------
// first = side[:,0] @ Wemb + bemb  -> y[:, 0, :]  (bf16)
// ---------------------------------------------------------------------------
__global__ __launch_bounds__(128)
void first_kernel(const float* __restrict__ side, const float* __restrict__ Wemb,
                  const float* __restrict__ bemb, ushort* __restrict__ yb) {
    const int o = blockIdx.x * 128 + threadIdx.x;   // 0..1151
    const int b = blockIdx.y;
    const float* s = side + (size_t)b * L_SEQ * D_SIDE;
    float acc = bemb[o];
    for (int k = 0; k < D_SIDE; k++)
        acc += s[k] * Wemb[(size_t)k * D_OUT + o];
    yb[(size_t)b * L_SEQ * D_OUT + o] = f2b(acc);
}

// ---------------------------------------------------------------------------
extern "C" void kernel_launch(void* const* d_in, const int* in_sizes, int n_in,
                              void* d_out, int out_size, void* d_ws, size_t ws_size,
                              hipStream_t stream) {
    const float* x     = (const float*)d_in[0];
    const float* side  = (const float*)d_in[1];
    const float* Wq    = (const float*)d_in[2];
    const float* bq    = (const float*)d_in[3];
    const float* Wkv   = (const float*)d_in[4];
    const float* bkv   = (const float*)d_in[5];
    const float* Wproj = (const float*)d_in[6];
    const float* bproj = (const float*)d_in[7];
    const float* Wemb  = (const float*)d_in[8];
    const float* bemb  = (const float*)d_in[9];
    float* out = (float*)d_out;

    char* ws = (char*)d_ws;
    ushort* xs_bf   = (ushort*)(ws + 0);          // [4096][1152]  9437184 B
    ushort* wkvq_t  = (ushort*)(ws + 9437184);    // [1536][1152]  3538944 B
    ushort* wproj_t = (ushort*)(ws + 12976128);   // [1152][1152]  2654208 B
    ushort* qbuf    = (ushort*)(ws + 15630336);   // [4096][192]   1572864 B
    ushort* kbuf    = (ushort*)(ws + 17203200);   // [4096][192]   1572864 B
    ushort* vtg     = (ushort*)(ws + 18776064);   // [24][96][2048] 9437184 B
    ushort* ybuf    = (ushort*)(ws + 28213248);   // [4096][1152]  9437184 B

    // prep: bf16 concat + weight transposes (3 launches)
    cvt_inputs<<<4608, 256, 0, stream>>>(x, side, xs_bf);
    transpose_kvq<<<dim3(48, 36), 256, 0, stream>>>(Wkv, Wq, wkvq_t);
    transpose_cvt<<<dim3(36, 36), 256, 0, stream>>>(Wproj, wproj_t, D_OUT, D_OUT);

    // fused kvq GEMM: [x,side]@[Wkv | 0;Wq] -> kbuf, vtg (transposed), qbuf
    gemm_mfma<2><<<dim3(12, 32), 256, 0, stream>>>(
        xs_bf, wkvq_t, bkv, bq, kbuf, vtg, qbuf, M_ROWS, D_KVQ, D_OUT);

    // attention (MFMA flash, 32-row tiles) -> ybuf bf16
    attn_mfma<<<1536, 128, 0, stream>>>(qbuf, kbuf, vtg, ybuf);

    // first-token override (row 0 of each batch) -- after attn
    first_kernel<<<dim3(9, BATCH), 128, 0, stream>>>(side, Wemb, bemb, ybuf);

    // out = y @ Wproj + bproj -> f32
    gemm_mfma<0><<<dim3(9, 32), 256, 0, stream>>>(
        ybuf, wproj_t, bproj, nullptr, out, nullptr, nullptr, M_ROWS, D_OUT, D_OUT);
}